// Round 4
// baseline (691.538 us; speedup 1.0000x reference)
//
#include <hip/hip_runtime.h>
#include <math.h>

// Problem constants (from reference)
#define NCH 129
#define BS 8
#define TLEN 64000
#define LFRM 256          // frame stride == chunk length
#define NFRM 250          // number of frames / chunks
#define NSEQ (NCH * BS)   // 1032 sequences
#define NBK (BS * NFRM)   // 2000 (b,k) tiles
#define EDGE_BLOCKS 32    // ceil(NBK/64) blocks handling channel-128

// Warm-up split: first WARM_IIR steps of the previous chunk evolve the IIR
// state only; sigmoid+beta accumulate over the last LFRM-WARM_IIR steps.
// beta^128 = e^-16 -> truncation ~1e-7, alpha-sum amplification <=128x -> ~1e-5.
#define WARM_IIR 128

struct Coef { float b0, b1, b2, b3, b4, a1, a2, a3, a4; };

__device__ __forceinline__ Coef load_coef(const float* __restrict__ B,
                                          const float* __restrict__ A, int c) {
    Coef q;
    q.b0 = B[c * 5 + 0]; q.b1 = B[c * 5 + 1]; q.b2 = B[c * 5 + 2];
    q.b3 = B[c * 5 + 3]; q.b4 = B[c * 5 + 4];
    q.a1 = A[c * 5 + 1]; q.a2 = A[c * 5 + 2];
    q.a3 = A[c * 5 + 3]; q.a4 = A[c * 5 + 4];
    return q;
}

// Direct-form II transposed, order 4.
__device__ __forceinline__ float iir_step(const Coef& q, float x,
                                          float& z0, float& z1, float& z2, float& z3) {
    float y = fmaf(q.b0, x, z0);
    z0 = fmaf(-q.a1, y, fmaf(q.b1, x, z1));
    z1 = fmaf(-q.a2, y, fmaf(q.b2, x, z2));
    z2 = fmaf(-q.a3, y, fmaf(q.b3, x, z3));
    z3 = fmaf(-q.a4, y, q.b4 * x);
    return y;
}

// rcp-based sigmoid: 2 transcendental + 2 simple ops.
__device__ __forceinline__ float sigmoidf(float x) {
    return __builtin_amdgcn_rcpf(1.0f + __expf(-x));
}

// ---------------------------------------------------------------------------
// Kernel A: per (c, b, chunk) zero-state order-4 IIR over the chunk -> final
// 4-state (forced response). x read as wave-uniform float4 groups (one
// cacheline per wave-load, no LDS, no barrier).
// zs layout: float4 at [k * NSEQ + (c*BS+b)].
// ---------------------------------------------------------------------------
__global__ __launch_bounds__(192, 4) void kA_forced_state(
        const float* __restrict__ wav, const float* __restrict__ B,
        const float* __restrict__ A, float* __restrict__ zs) {
    int blk = blockIdx.x;            // b * NFRM + k
    int b = blk / NFRM;
    int k = blk - b * NFRM;
    int c = threadIdx.x;
    if (c >= NCH) return;
    const float4* xv = (const float4*)(wav + (size_t)b * TLEN + (size_t)k * LFRM);
    Coef q = load_coef(B, A, c);
    float z0 = 0.f, z1 = 0.f, z2 = 0.f, z3 = 0.f;
    #pragma unroll 2
    for (int g = 0; g < LFRM / 4; ++g) {
        float4 xq = xv[g];
        (void)iir_step(q, xq.x, z0, z1, z2, z3);
        (void)iir_step(q, xq.y, z0, z1, z2, z3);
        (void)iir_step(q, xq.z, z0, z1, z2, z3);
        (void)iir_step(q, xq.w, z0, z1, z2, z3);
    }
    ((float4*)zs)[(size_t)k * NSEQ + (c * BS + b)] = make_float4(z0, z1, z2, z3);
}

// ---------------------------------------------------------------------------
// Kernel B: per (c,b) sequence — M^256 by repeated squaring, then scan:
//   z_in[k] = M^L * z_in[k-1] + d[k-1],  z_in[0] = 0  (in place, k-major).
// ---------------------------------------------------------------------------
__global__ __launch_bounds__(64) void kB_state_scan(
        const float* __restrict__ A, float* __restrict__ zs) {
    int id = blockIdx.x * 64 + threadIdx.x;   // c * BS + b
    if (id >= NSEQ) return;
    int c = id / BS;
    float a1 = A[c * 5 + 1], a2 = A[c * 5 + 2], a3 = A[c * 5 + 3], a4 = A[c * 5 + 4];
    float M[4][4] = {{-a1, 1.f, 0.f, 0.f},
                     {-a2, 0.f, 1.f, 0.f},
                     {-a3, 0.f, 0.f, 1.f},
                     {-a4, 0.f, 0.f, 0.f}};
    for (int s = 0; s < 8; ++s) {        // M^(2^8) = M^256
        float R[4][4];
        for (int i = 0; i < 4; ++i)
            for (int j = 0; j < 4; ++j) {
                float acc = 0.f;
                for (int t = 0; t < 4; ++t) acc = fmaf(M[i][t], M[t][j], acc);
                R[i][j] = acc;
            }
        for (int i = 0; i < 4; ++i)
            for (int j = 0; j < 4; ++j) M[i][j] = R[i][j];
    }
    float4* zb = (float4*)zs;
    float s0 = 0.f, s1 = 0.f, s2 = 0.f, s3 = 0.f;
    for (int k = 0; k < NFRM; k += 5) {            // 250 = 5*50
        float4 d[5];
        #pragma unroll
        for (int u = 0; u < 5; ++u) d[u] = zb[(size_t)(k + u) * NSEQ + id];
        #pragma unroll
        for (int u = 0; u < 5; ++u) {
            zb[(size_t)(k + u) * NSEQ + id] = make_float4(s0, s1, s2, s3);
            float n0 = fmaf(M[0][0], s0, fmaf(M[0][1], s1, fmaf(M[0][2], s2, fmaf(M[0][3], s3, d[u].x))));
            float n1 = fmaf(M[1][0], s0, fmaf(M[1][1], s1, fmaf(M[1][2], s2, fmaf(M[1][3], s3, d[u].y))));
            float n2 = fmaf(M[2][0], s0, fmaf(M[2][1], s1, fmaf(M[2][2], s2, fmaf(M[2][3], s3, d[u].z))));
            float n3 = fmaf(M[3][0], s0, fmaf(M[3][1], s1, fmaf(M[3][2], s2, fmaf(M[3][3], s3, d[u].w))));
            s0 = n0; s1 = n1; s2 = n2; s3 = n3;
        }
    }
}

// ---------------------------------------------------------------------------
// Kernel C (combined): blocks [0, EDGE_BLOCKS) handle channel-128 (one thread
// per (b,k), chains 127&128, gathered float4 x reads) — dispatched first so
// they run concurrently under the main blocks. Blocks [EDGE_BLOCKS, +NBK):
// pair-channel main — one wave per (b,k); lane t runs chains 2t & 2t+1 from
// exact z_in[k-1] (warm-up over chunk k-1 for the beta state), emits y4-terms
// for channels 2t+1 (local) and 2t+2 (shfl_down).
// x reads are wave-uniform float4 groups (no LDS, no barrier).
// G/y4f layout: [(b*NFRM+k)*NCH + c].
// ---------------------------------------------------------------------------
__global__ __launch_bounds__(64, 4) void kC_main(
        const float* __restrict__ wav, const float* __restrict__ B,
        const float* __restrict__ A, const float* __restrict__ zs,
        float* __restrict__ G, float* __restrict__ y4f,
        float beta, float alpha) {
    int blk = blockIdx.x;

    if (blk < EDGE_BLOCKS) {
        // ---- edge: channel 128, one thread per (b,k) ----
        int item = blk * 64 + threadIdx.x;   // b * NFRM + k
        if (item >= NBK) return;
        int b = item / NFRM;
        int k = item - b * NFRM;
        int kload = (k > 0) ? (k - 1) : 0;
        const float4* xv = (const float4*)(wav + (size_t)b * TLEN + (size_t)kload * LFRM);
        Coef qa = load_coef(B, A, 128);
        Coef qb = load_coef(B, A, 127);
        float za0 = 0.f, za1 = 0.f, za2 = 0.f, za3 = 0.f;
        float zb0 = 0.f, zb1 = 0.f, zb2 = 0.f, zb3 = 0.f;
        float ua = 0.f, ub = 0.f;
        int goff = 0;
        if (k > 0) {
            float4 va = ((const float4*)zs)[(size_t)(k - 1) * NSEQ + (128 * BS + b)];
            float4 vb = ((const float4*)zs)[(size_t)(k - 1) * NSEQ + (127 * BS + b)];
            za0 = va.x; za1 = va.y; za2 = va.z; za3 = va.w;
            zb0 = vb.x; zb1 = vb.y; zb2 = vb.z; zb3 = vb.w;
            for (int g = 0; g < WARM_IIR / 4; ++g) {
                float4 xq = xv[g];
                float xs4[4] = {xq.x, xq.y, xq.z, xq.w};
                #pragma unroll
                for (int u = 0; u < 4; ++u) {
                    (void)iir_step(qa, xs4[u], za0, za1, za2, za3);
                    (void)iir_step(qb, xs4[u], zb0, zb1, zb2, zb3);
                }
            }
            for (int g = WARM_IIR / 4; g < LFRM / 4; ++g) {
                float4 xq = xv[g];
                float xs4[4] = {xq.x, xq.y, xq.z, xq.w};
                #pragma unroll
                for (int u = 0; u < 4; ++u) {
                    float ya = iir_step(qa, xs4[u], za0, za1, za2, za3);
                    float yb = iir_step(qb, xs4[u], zb0, zb1, zb2, zb3);
                    ua = fmaf(beta, ua, sigmoidf(ya));
                    ub = fmaf(beta, ub, sigmoidf(yb));
                }
            }
            goff = LFRM / 4;
        }
        float g4 = 0.f, yfirst = 0.f;
        bool first = true;
        for (int g = 0; g < LFRM / 4; ++g) {
            float4 xq = xv[goff + g];
            float xs4[4] = {xq.x, xq.y, xq.z, xq.w};
            #pragma unroll
            for (int u = 0; u < 4; ++u) {
                float ya = iir_step(qa, xs4[u], za0, za1, za2, za3);
                float yb = iir_step(qb, xs4[u], zb0, zb1, zb2, zb3);
                ua = fmaf(beta, ua, sigmoidf(ya));
                ub = fmaf(beta, ub, sigmoidf(yb));
                float y4 = fmaxf(ua - ub, 0.0f);
                if (first && u == 0) { yfirst = y4; first = false; }
                g4 = fmaf(alpha, g4, y4);
            }
        }
        size_t idx = (size_t)item * NCH + 128;
        G[idx] = g4;
        y4f[idx] = yfirst;
        return;
    }

    // ---- main: one wave per (b,k); lane t -> chains 2t, 2t+1 ----
    int mblk = blk - EDGE_BLOCKS;            // b * NFRM + k
    int b = mblk / NFRM;
    int k = mblk - b * NFRM;
    int t = threadIdx.x;                     // 0..63
    int cA = 2 * t, cB = 2 * t + 1;          // chains (cB <= 127)
    Coef qa = load_coef(B, A, cA);
    Coef qb = load_coef(B, A, cB);
    float za0 = 0.f, za1 = 0.f, za2 = 0.f, za3 = 0.f;
    float zb0 = 0.f, zb1 = 0.f, zb2 = 0.f, zb3 = 0.f;
    float ua = 0.f, ub = 0.f;

    const float4* xv;
    if (k > 0) {
        xv = (const float4*)(wav + (size_t)b * TLEN + (size_t)(k - 1) * LFRM);
        float4 va = ((const float4*)zs)[(size_t)(k - 1) * NSEQ + (cA * BS + b)];
        float4 vb = ((const float4*)zs)[(size_t)(k - 1) * NSEQ + (cB * BS + b)];
        za0 = va.x; za1 = va.y; za2 = va.z; za3 = va.w;
        zb0 = vb.x; zb1 = vb.y; zb2 = vb.z; zb3 = vb.w;
        // head of warm-up chunk: IIR state evolution only
        #pragma unroll 2
        for (int g = 0; g < WARM_IIR / 4; ++g) {
            float4 xq = xv[g];
            float xs4[4] = {xq.x, xq.y, xq.z, xq.w};
            #pragma unroll
            for (int u = 0; u < 4; ++u) {
                (void)iir_step(qa, xs4[u], za0, za1, za2, za3);
                (void)iir_step(qb, xs4[u], zb0, zb1, zb2, zb3);
            }
        }
        // tail of warm-up chunk: IIR + sigmoid + beta
        #pragma unroll 2
        for (int g = WARM_IIR / 4; g < LFRM / 4; ++g) {
            float4 xq = xv[g];
            float xs4[4] = {xq.x, xq.y, xq.z, xq.w};
            #pragma unroll
            for (int u = 0; u < 4; ++u) {
                float ya = iir_step(qa, xs4[u], za0, za1, za2, za3);
                float yb = iir_step(qb, xs4[u], zb0, zb1, zb2, zb3);
                ua = fmaf(beta, ua, sigmoidf(ya));
                ub = fmaf(beta, ub, sigmoidf(yb));
            }
        }
        xv += LFRM / 4;   // advance to chunk k
    } else {
        xv = (const float4*)(wav + (size_t)b * TLEN);
    }

    float go, ge, fo, fe;
    {   // group 0: peel j=0 (capture y4[t0]), then j=1..3
        float4 xq = xv[0];
        float ya = iir_step(qa, xq.x, za0, za1, za2, za3);
        float yb = iir_step(qb, xq.x, zb0, zb1, zb2, zb3);
        ua = fmaf(beta, ua, sigmoidf(ya));
        ub = fmaf(beta, ub, sigmoidf(yb));
        float un = __shfl_down(ua, 1, 64);
        fo = go = fmaxf(ub - ua, 0.0f);
        fe = ge = fmaxf(un - ub, 0.0f);
        float xs3[3] = {xq.y, xq.z, xq.w};
        #pragma unroll
        for (int u = 0; u < 3; ++u) {
            float ya2 = iir_step(qa, xs3[u], za0, za1, za2, za3);
            float yb2 = iir_step(qb, xs3[u], zb0, zb1, zb2, zb3);
            ua = fmaf(beta, ua, sigmoidf(ya2));
            ub = fmaf(beta, ub, sigmoidf(yb2));
            float un2 = __shfl_down(ua, 1, 64);
            go = fmaf(alpha, go, fmaxf(ub - ua, 0.0f));
            ge = fmaf(alpha, ge, fmaxf(un2 - ub, 0.0f));
        }
    }
    #pragma unroll 2
    for (int g = 1; g < LFRM / 4; ++g) {
        float4 xq = xv[g];
        float xs4[4] = {xq.x, xq.y, xq.z, xq.w};
        #pragma unroll
        for (int u = 0; u < 4; ++u) {
            float ya = iir_step(qa, xs4[u], za0, za1, za2, za3);
            float yb = iir_step(qb, xs4[u], zb0, zb1, zb2, zb3);
            ua = fmaf(beta, ua, sigmoidf(ya));
            ub = fmaf(beta, ub, sigmoidf(yb));
            float un = __shfl_down(ua, 1, 64);
            go = fmaf(alpha, go, fmaxf(ub - ua, 0.0f));
            ge = fmaf(alpha, ge, fmaxf(un - ub, 0.0f));
        }
    }
    size_t base = (size_t)mblk * NCH;
    G[base + cB] = go;            // channel 2t+1 (odd 1..127)
    y4f[base + cB] = fo;
    if (t < 63) {
        G[base + cB + 1] = ge;    // channel 2t+2 (even 2..126)
        y4f[base + cB + 1] = fe;
    }
}

// ---------------------------------------------------------------------------
// Kernel D: per (b,c) exclusive alpha-scan over chunks.
//   y5[256k] = alpha * s_in[k] + y4[256k];  s_in[k+1] = alpha^L s_in[k] + G[k].
// ---------------------------------------------------------------------------
__global__ __launch_bounds__(64) void kD_alpha_scan(
        const float* __restrict__ G, const float* __restrict__ y4f,
        float* __restrict__ out, float alpha, float alphaL) {
    int id = blockIdx.x * 64 + threadIdx.x;   // b * NCH + c
    if (id >= NSEQ) return;
    int b = id / NCH;
    int c = id - b * NCH;
    float* o = out + (size_t)id * NFRM;       // (BS, NCH, NFRM) row
    if (c == 0) {
        for (int k = 0; k < NFRM; ++k) o[k] = 0.0f;
        return;
    }
    float s = 0.f;
    for (int k = 0; k < NFRM; k += 5) {       // 250 = 5*50
        float gk[5], yk[5];
        #pragma unroll
        for (int u = 0; u < 5; ++u) {
            size_t idx = ((size_t)b * NFRM + (k + u)) * NCH + c;
            gk[u] = G[idx];
            yk[u] = y4f[idx];
        }
        #pragma unroll
        for (int u = 0; u < 5; ++u) {
            o[k + u] = fmaf(alpha, s, yk[u]);
            s = fmaf(alphaL, s, gk[u]);
        }
    }
}

// ---------------------------------------------------------------------------
extern "C" void kernel_launch(void* const* d_in, const int* in_sizes, int n_in,
                              void* d_out, int out_size, void* d_ws, size_t ws_size,
                              hipStream_t stream) {
    const float* wav = (const float*)d_in[0];   // (BS, TLEN)
    const float* Bc  = (const float*)d_in[1];   // (NCH, 5)
    const float* Ac  = (const float*)d_in[2];   // (NCH, 5)
    float* out = (float*)d_out;                 // (BS, NCH, NFRM)

    // workspace: zs (NFRM*NSEQ float4) | G (NBK*NCH) | y4f (NBK*NCH)
    float* zs  = (float*)d_ws;
    float* G   = zs + (size_t)NFRM * NSEQ * 4;
    float* y4f = G + (size_t)NBK * NCH;

    const float alpha  = (float)exp(-1.0 / 128.0);
    const float beta   = (float)exp(-1.0 / 8.0);
    const float alphaL = (float)exp(-256.0 / 128.0);

    kA_forced_state<<<NBK, 192, 0, stream>>>(wav, Bc, Ac, zs);
    kB_state_scan<<<(NSEQ + 63) / 64, 64, 0, stream>>>(Ac, zs);
    kC_main<<<EDGE_BLOCKS + NBK, 64, 0, stream>>>(wav, Bc, Ac, zs, G, y4f, beta, alpha);
    kD_alpha_scan<<<(NSEQ + 63) / 64, 64, 0, stream>>>(G, y4f, out, alpha, alphaL);
}

// Round 5
// 221.207 us; speedup vs baseline: 3.1262x; 3.1262x over previous
//
#include <hip/hip_runtime.h>
#include <math.h>

// Problem constants (from reference)
#define NCH 129
#define BS 8
#define TLEN 64000
#define HALF 128          // state-granularity half-chunk
#define NH 500            // TLEN / HALF
#define LFRM 256          // frame stride == main-chunk length
#define NFRM 250          // number of frames
#define NSEQ (NCH * BS)   // 1032 sequences
#define NBK (BS * NFRM)   // 2000 (b,k) tiles
#define EDGE_BLOCKS 32    // ceil(NBK/64) blocks handling channel-128

struct Coef { float b0, b1, b2, b3, b4, a1, a2, a3, a4; };

__device__ __forceinline__ Coef load_coef(const float* __restrict__ B,
                                          const float* __restrict__ A, int c) {
    Coef q;
    q.b0 = B[c * 5 + 0]; q.b1 = B[c * 5 + 1]; q.b2 = B[c * 5 + 2];
    q.b3 = B[c * 5 + 3]; q.b4 = B[c * 5 + 4];
    q.a1 = A[c * 5 + 1]; q.a2 = A[c * 5 + 2];
    q.a3 = A[c * 5 + 3]; q.a4 = A[c * 5 + 4];
    return q;
}

// Direct-form II transposed, order 4.
__device__ __forceinline__ float iir_step(const Coef& q, float x,
                                          float& z0, float& z1, float& z2, float& z3) {
    float y = fmaf(q.b0, x, z0);
    z0 = fmaf(-q.a1, y, fmaf(q.b1, x, z1));
    z1 = fmaf(-q.a2, y, fmaf(q.b2, x, z2));
    z2 = fmaf(-q.a3, y, fmaf(q.b3, x, z3));
    z3 = fmaf(-q.a4, y, q.b4 * x);
    return y;
}

// rcp-based sigmoid: 2 transcendental + 2 simple ops.
__device__ __forceinline__ float sigmoidf(float x) {
    return __builtin_amdgcn_rcpf(1.0f + __expf(-x));
}

// ---------------------------------------------------------------------------
// Kernel A: per (c, b, half-chunk h) zero-state order-4 IIR over 128 samples
// -> final 4-state (forced response). LDS-staged x (proven round-3 pattern).
// zs layout: float4 at [h * NSEQ + (c*BS+b)], h in [0, NH).
// ---------------------------------------------------------------------------
__global__ __launch_bounds__(192, 4) void kA_forced_state(
        const float* __restrict__ wav, const float* __restrict__ B,
        const float* __restrict__ A, float* __restrict__ zs) {
    __shared__ float xs[HALF];
    int blk = blockIdx.x;            // b * NH + h
    int b = blk / NH;
    int h = blk - b * NH;
    const float* xg = wav + (size_t)b * TLEN + (size_t)h * HALF;
    if (threadIdx.x < HALF) xs[threadIdx.x] = xg[threadIdx.x];
    __syncthreads();
    int c = threadIdx.x;
    if (c >= NCH) return;
    Coef q = load_coef(B, A, c);
    float z0 = 0.f, z1 = 0.f, z2 = 0.f, z3 = 0.f;
    #pragma unroll 8
    for (int j = 0; j < HALF; ++j) {
        (void)iir_step(q, xs[j], z0, z1, z2, z3);
    }
    ((float4*)zs)[(size_t)h * NSEQ + (c * BS + b)] = make_float4(z0, z1, z2, z3);
}

// ---------------------------------------------------------------------------
// Kernel B: per (c,b) sequence — M^128 by repeated squaring (7 squarings),
// then scan 500 half-chunk states in place (k-major -> coalesced), with
// explicit software-pipelined prefetch (named float4 scalars, no arrays).
//   z_in[h] = M^HALF * z_in[h-1] + d[h-1],  z_in[0] = 0.
// ---------------------------------------------------------------------------
#define KB_PROC(d, kk)                                                         \
    {                                                                          \
        zb[(size_t)(kk) * NSEQ + id] = make_float4(s0, s1, s2, s3);            \
        float n0 = fmaf(M00, s0, fmaf(M01, s1, fmaf(M02, s2, fmaf(M03, s3, (d).x)))); \
        float n1 = fmaf(M10, s0, fmaf(M11, s1, fmaf(M12, s2, fmaf(M13, s3, (d).y)))); \
        float n2 = fmaf(M20, s0, fmaf(M21, s1, fmaf(M22, s2, fmaf(M23, s3, (d).z)))); \
        float n3 = fmaf(M30, s0, fmaf(M31, s1, fmaf(M32, s2, fmaf(M33, s3, (d).w)))); \
        s0 = n0; s1 = n1; s2 = n2; s3 = n3;                                    \
    }

__global__ __launch_bounds__(64) void kB_state_scan(
        const float* __restrict__ A, float* __restrict__ zs) {
    int id = blockIdx.x * 64 + threadIdx.x;   // c * BS + b
    if (id >= NSEQ) return;
    int c = id / BS;
    float a1 = A[c * 5 + 1], a2 = A[c * 5 + 2], a3 = A[c * 5 + 3], a4 = A[c * 5 + 4];
    float M00 = -a1, M01 = 1.f, M02 = 0.f, M03 = 0.f;
    float M10 = -a2, M11 = 0.f, M12 = 1.f, M13 = 0.f;
    float M20 = -a3, M21 = 0.f, M22 = 0.f, M23 = 1.f;
    float M30 = -a4, M31 = 0.f, M32 = 0.f, M33 = 0.f;
    for (int s = 0; s < 7; ++s) {        // M^(2^7) = M^128
        float R00 = fmaf(M00, M00, fmaf(M01, M10, fmaf(M02, M20, M03 * M30)));
        float R01 = fmaf(M00, M01, fmaf(M01, M11, fmaf(M02, M21, M03 * M31)));
        float R02 = fmaf(M00, M02, fmaf(M01, M12, fmaf(M02, M22, M03 * M32)));
        float R03 = fmaf(M00, M03, fmaf(M01, M13, fmaf(M02, M23, M03 * M33)));
        float R10 = fmaf(M10, M00, fmaf(M11, M10, fmaf(M12, M20, M13 * M30)));
        float R11 = fmaf(M10, M01, fmaf(M11, M11, fmaf(M12, M21, M13 * M31)));
        float R12 = fmaf(M10, M02, fmaf(M11, M12, fmaf(M12, M22, M13 * M32)));
        float R13 = fmaf(M10, M03, fmaf(M11, M13, fmaf(M12, M23, M13 * M33)));
        float R20 = fmaf(M20, M00, fmaf(M21, M10, fmaf(M22, M20, M23 * M30)));
        float R21 = fmaf(M20, M01, fmaf(M21, M11, fmaf(M22, M21, M23 * M31)));
        float R22 = fmaf(M20, M02, fmaf(M21, M12, fmaf(M22, M22, M23 * M32)));
        float R23 = fmaf(M20, M03, fmaf(M21, M13, fmaf(M22, M23, M23 * M33)));
        float R30 = fmaf(M30, M00, fmaf(M31, M10, fmaf(M32, M20, M33 * M30)));
        float R31 = fmaf(M30, M01, fmaf(M31, M11, fmaf(M32, M21, M33 * M31)));
        float R32 = fmaf(M30, M02, fmaf(M31, M12, fmaf(M32, M22, M33 * M32)));
        float R33 = fmaf(M30, M03, fmaf(M31, M13, fmaf(M32, M23, M33 * M33)));
        M00 = R00; M01 = R01; M02 = R02; M03 = R03;
        M10 = R10; M11 = R11; M12 = R12; M13 = R13;
        M20 = R20; M21 = R21; M22 = R22; M23 = R23;
        M30 = R30; M31 = R31; M32 = R32; M33 = R33;
    }
    float4* zb = (float4*)zs;
    float s0 = 0.f, s1 = 0.f, s2 = 0.f, s3 = 0.f;
    // prefetch group 0
    float4 c0 = zb[(size_t)0 * NSEQ + id];
    float4 c1 = zb[(size_t)1 * NSEQ + id];
    float4 c2 = zb[(size_t)2 * NSEQ + id];
    float4 c3 = zb[(size_t)3 * NSEQ + id];
    float4 c4 = zb[(size_t)4 * NSEQ + id];
    for (int k = 0; k < NH; k += 5) {          // 500 = 5*100
        float4 p0 = c0, p1 = c1, p2 = c2, p3 = c3, p4 = c4;
        if (k + 5 < NH) {
            p0 = zb[(size_t)(k + 5) * NSEQ + id];
            p1 = zb[(size_t)(k + 6) * NSEQ + id];
            p2 = zb[(size_t)(k + 7) * NSEQ + id];
            p3 = zb[(size_t)(k + 8) * NSEQ + id];
            p4 = zb[(size_t)(k + 9) * NSEQ + id];
        }
        KB_PROC(c0, k + 0);
        KB_PROC(c1, k + 1);
        KB_PROC(c2, k + 2);
        KB_PROC(c3, k + 3);
        KB_PROC(c4, k + 4);
        c0 = p0; c1 = p1; c2 = p2; c3 = p3; c4 = p4;
    }
}

// ---------------------------------------------------------------------------
// Kernel C (combined):
// Blocks [0, EDGE_BLOCKS): channel-128 path — one thread per (b,k), chains
//   127 & 128, scalar global x reads (round-3 proven shape). Dispatched first
//   so these blocks hide under the main blocks.
// Blocks [EDGE_BLOCKS, +NBK): pair-channel main — one wave per (b,k); lane t
//   runs chains 2t & 2t+1 starting from the EXACT state at sample 256k-128
//   (half-chunk 2k-1), 128 full warm-up steps (beta^128 = e^-16 truncation),
//   then 256 main steps emitting y4-terms for channels 2t+1 (local) and
//   2t+2 (shfl_down). x staged in LDS (384 floats).
// G/y4f layout: [(b*NFRM+k)*NCH + c].
// ---------------------------------------------------------------------------
__global__ __launch_bounds__(64, 4) void kC_main(
        const float* __restrict__ wav, const float* __restrict__ B,
        const float* __restrict__ A, const float* __restrict__ zs,
        float* __restrict__ G, float* __restrict__ y4f,
        float beta, float alpha) {
    __shared__ float xs[3 * HALF];
    int blk = blockIdx.x;

    if (blk < EDGE_BLOCKS) {
        // ---- edge: channel 128, one thread per (b,k) ----
        int item = blk * 64 + threadIdx.x;   // b * NFRM + k
        if (item >= NBK) return;
        int b = item / NFRM;
        int k = item - b * NFRM;
        Coef qa = load_coef(B, A, 128);
        Coef qb = load_coef(B, A, 127);
        float za0 = 0.f, za1 = 0.f, za2 = 0.f, za3 = 0.f;
        float zb0 = 0.f, zb1 = 0.f, zb2 = 0.f, zb3 = 0.f;
        float ua = 0.f, ub = 0.f;
        const float* xg;
        if (k > 0) {
            float4 va = ((const float4*)zs)[(size_t)(2 * k - 1) * NSEQ + (128 * BS + b)];
            float4 vb = ((const float4*)zs)[(size_t)(2 * k - 1) * NSEQ + (127 * BS + b)];
            za0 = va.x; za1 = va.y; za2 = va.z; za3 = va.w;
            zb0 = vb.x; zb1 = vb.y; zb2 = vb.z; zb3 = vb.w;
            xg = wav + (size_t)b * TLEN + ((size_t)k * LFRM - HALF);
            #pragma unroll 2
            for (int j = 0; j < HALF; ++j) {
                float x = xg[j];
                float ya = iir_step(qa, x, za0, za1, za2, za3);
                float yb = iir_step(qb, x, zb0, zb1, zb2, zb3);
                ua = fmaf(beta, ua, sigmoidf(ya));
                ub = fmaf(beta, ub, sigmoidf(yb));
            }
            xg += HALF;
        } else {
            xg = wav + (size_t)b * TLEN;
        }
        float g4 = 0.f, yfirst = 0.f;
        #pragma unroll 2
        for (int j = 0; j < LFRM; ++j) {
            float x = xg[j];
            float ya = iir_step(qa, x, za0, za1, za2, za3);
            float yb = iir_step(qb, x, zb0, zb1, zb2, zb3);
            ua = fmaf(beta, ua, sigmoidf(ya));
            ub = fmaf(beta, ub, sigmoidf(yb));
            float y4 = fmaxf(ua - ub, 0.0f);
            if (j == 0) yfirst = y4;
            g4 = fmaf(alpha, g4, y4);
        }
        size_t idx = (size_t)item * NCH + 128;
        G[idx] = g4;
        y4f[idx] = yfirst;
        return;
    }

    // ---- main: one wave per (b,k); lane t -> chains 2t, 2t+1 ----
    int mblk = blk - EDGE_BLOCKS;            // b * NFRM + k
    int b = mblk / NFRM;
    int k = mblk - b * NFRM;
    int nload = (k > 0) ? 3 * HALF : LFRM;
    const float* xg = wav + (size_t)b * TLEN +
                      ((k > 0) ? ((size_t)k * LFRM - HALF) : (size_t)0);
    for (int i = threadIdx.x; i < nload; i += 64) xs[i] = xg[i];
    __syncthreads();

    int t = threadIdx.x;                     // 0..63
    int cA = 2 * t, cB = 2 * t + 1;          // chains (cB <= 127)
    Coef qa = load_coef(B, A, cA);
    Coef qb = load_coef(B, A, cB);
    float za0 = 0.f, za1 = 0.f, za2 = 0.f, za3 = 0.f;
    float zb0 = 0.f, zb1 = 0.f, zb2 = 0.f, zb3 = 0.f;
    float ua = 0.f, ub = 0.f;
    int off = 0;
    if (k > 0) {
        float4 va = ((const float4*)zs)[(size_t)(2 * k - 1) * NSEQ + (cA * BS + b)];
        float4 vb = ((const float4*)zs)[(size_t)(2 * k - 1) * NSEQ + (cB * BS + b)];
        za0 = va.x; za1 = va.y; za2 = va.z; za3 = va.w;
        zb0 = vb.x; zb1 = vb.y; zb2 = vb.z; zb3 = vb.w;
        // warm-up: 128 full steps (IIR + sigmoid + beta) from exact state
        #pragma unroll 2
        for (int j = 0; j < HALF; ++j) {
            float x = xs[j];
            float ya = iir_step(qa, x, za0, za1, za2, za3);
            float yb = iir_step(qb, x, zb0, zb1, zb2, zb3);
            ua = fmaf(beta, ua, sigmoidf(ya));
            ub = fmaf(beta, ub, sigmoidf(yb));
        }
        off = HALF;
    }
    float go = 0.f, ge = 0.f, fo = 0.f, fe = 0.f;
    #pragma unroll 2
    for (int j = 0; j < LFRM; ++j) {
        float x = xs[off + j];
        float ya = iir_step(qa, x, za0, za1, za2, za3);
        float yb = iir_step(qb, x, zb0, zb1, zb2, zb3);
        ua = fmaf(beta, ua, sigmoidf(ya));
        ub = fmaf(beta, ub, sigmoidf(yb));
        float un = __shfl_down(ua, 1, 64);   // chain 2t+2's u (lane t+1)
        float y4o = fmaxf(ub - ua, 0.0f);    // channel 2t+1
        float y4e = fmaxf(un - ub, 0.0f);    // channel 2t+2
        if (j == 0) { fo = y4o; fe = y4e; }
        go = fmaf(alpha, go, y4o);
        ge = fmaf(alpha, ge, y4e);
    }
    size_t base = (size_t)mblk * NCH;
    G[base + cB] = go;            // channel 2t+1 (odd 1..127)
    y4f[base + cB] = fo;
    if (t < 63) {
        G[base + cB + 1] = ge;    // channel 2t+2 (even 2..126)
        y4f[base + cB + 1] = fe;
    }
}

// ---------------------------------------------------------------------------
// Kernel D: per (b,c) exclusive alpha-scan over chunks.
//   y5[256k] = alpha * s_in[k] + y4[256k];  s_in[k+1] = alpha^L s_in[k] + G[k].
// ---------------------------------------------------------------------------
__global__ __launch_bounds__(64) void kD_alpha_scan(
        const float* __restrict__ G, const float* __restrict__ y4f,
        float* __restrict__ out, float alpha, float alphaL) {
    int id = blockIdx.x * 64 + threadIdx.x;   // b * NCH + c
    if (id >= NSEQ) return;
    int b = id / NCH;
    int c = id - b * NCH;
    float* o = out + (size_t)id * NFRM;       // (BS, NCH, NFRM) row
    if (c == 0) {
        for (int k = 0; k < NFRM; ++k) o[k] = 0.0f;
        return;
    }
    float s = 0.f;
    for (int k = 0; k < NFRM; k += 5) {       // 250 = 5*50
        float g0, g1, g2, g3, g4, y0, y1, y2, y3, y4;
        size_t i0 = ((size_t)b * NFRM + k) * NCH + c;
        g0 = G[i0];            y0 = y4f[i0];
        g1 = G[i0 + NCH];      y1 = y4f[i0 + NCH];
        g2 = G[i0 + 2 * NCH];  y2 = y4f[i0 + 2 * NCH];
        g3 = G[i0 + 3 * NCH];  y3 = y4f[i0 + 3 * NCH];
        g4 = G[i0 + 4 * NCH];  y4 = y4f[i0 + 4 * NCH];
        o[k + 0] = fmaf(alpha, s, y0); s = fmaf(alphaL, s, g0);
        o[k + 1] = fmaf(alpha, s, y1); s = fmaf(alphaL, s, g1);
        o[k + 2] = fmaf(alpha, s, y2); s = fmaf(alphaL, s, g2);
        o[k + 3] = fmaf(alpha, s, y3); s = fmaf(alphaL, s, g3);
        o[k + 4] = fmaf(alpha, s, y4); s = fmaf(alphaL, s, g4);
    }
}

// ---------------------------------------------------------------------------
extern "C" void kernel_launch(void* const* d_in, const int* in_sizes, int n_in,
                              void* d_out, int out_size, void* d_ws, size_t ws_size,
                              hipStream_t stream) {
    const float* wav = (const float*)d_in[0];   // (BS, TLEN)
    const float* Bc  = (const float*)d_in[1];   // (NCH, 5)
    const float* Ac  = (const float*)d_in[2];   // (NCH, 5)
    float* out = (float*)d_out;                 // (BS, NCH, NFRM)

    // workspace: zs (NH*NSEQ float4 = 8.26 MB) | G (NBK*NCH) | y4f (NBK*NCH)
    float* zs  = (float*)d_ws;
    float* G   = zs + (size_t)NH * NSEQ * 4;
    float* y4f = G + (size_t)NBK * NCH;

    const float alpha  = (float)exp(-1.0 / 128.0);
    const float beta   = (float)exp(-1.0 / 8.0);
    const float alphaL = (float)exp(-256.0 / 128.0);

    kA_forced_state<<<BS * NH, 192, 0, stream>>>(wav, Bc, Ac, zs);
    kB_state_scan<<<(NSEQ + 63) / 64, 64, 0, stream>>>(Ac, zs);
    kC_main<<<EDGE_BLOCKS + NBK, 64, 0, stream>>>(wav, Bc, Ac, zs, G, y4f, beta, alpha);
    kD_alpha_scan<<<(NSEQ + 63) / 64, 64, 0, stream>>>(G, y4f, out, alpha, alphaL);
}

// Round 6
// 203.973 us; speedup vs baseline: 3.3903x; 1.0845x over previous
//
#include <hip/hip_runtime.h>
#include <math.h>

// Problem constants (from reference)
#define NCH 129
#define BS 8
#define TLEN 64000
#define HALF 128          // state-granularity half-chunk
#define NH 500            // TLEN / HALF
#define LFRM 256          // frame stride == main-chunk length
#define NFRM 250          // number of frames
#define NSEQ (NCH * BS)   // 1032 sequences
#define NBK (BS * NFRM)   // 2000 (b,k) tiles
#define EDGE_BLOCKS 32    // ceil(NBK/64) blocks handling channel-128

typedef float f2 __attribute__((ext_vector_type(2)));

__device__ __forceinline__ f2 mk2(float a, float b) { f2 r; r.x = a; r.y = b; return r; }

__device__ __forceinline__ f2 fma2(f2 a, f2 b, f2 c) {
#if __has_builtin(__builtin_elementwise_fma)
    return __builtin_elementwise_fma(a, b, c);
#else
    f2 r; r.x = fmaf(a.x, b.x, c.x); r.y = fmaf(a.y, b.y, c.y); return r;
#endif
}

// rcp-based sigmoid on both components (exp/rcp are scalar pipes).
__device__ __forceinline__ f2 sig2(f2 v) {
    f2 r;
    r.x = __builtin_amdgcn_rcpf(1.0f + __expf(-v.x));
    r.y = __builtin_amdgcn_rcpf(1.0f + __expf(-v.y));
    return r;
}

// Packed pair-of-chains coefficients: component .x = first chain, .y = second.
struct C2 { f2 b0, b1, b2, b3, b4, a1, a2, a3, a4; };

__device__ __forceinline__ C2 load_coef2(const float* __restrict__ B,
                                         const float* __restrict__ A,
                                         int cx, int cy) {
    C2 q;
    q.b0 = mk2(B[cx * 5 + 0], B[cy * 5 + 0]);
    q.b1 = mk2(B[cx * 5 + 1], B[cy * 5 + 1]);
    q.b2 = mk2(B[cx * 5 + 2], B[cy * 5 + 2]);
    q.b3 = mk2(B[cx * 5 + 3], B[cy * 5 + 3]);
    q.b4 = mk2(B[cx * 5 + 4], B[cy * 5 + 4]);
    q.a1 = mk2(A[cx * 5 + 1], A[cy * 5 + 1]);
    q.a2 = mk2(A[cx * 5 + 2], A[cy * 5 + 2]);
    q.a3 = mk2(A[cx * 5 + 3], A[cy * 5 + 3]);
    q.a4 = mk2(A[cx * 5 + 4], A[cy * 5 + 4]);
    return q;
}

// Direct-form II transposed, order 4, two chains packed.
__device__ __forceinline__ f2 iir2_step(const C2& q, float x,
                                        f2& z0, f2& z1, f2& z2, f2& z3) {
    f2 xx = mk2(x, x);
    f2 y = fma2(q.b0, xx, z0);
    z0 = fma2(-q.a1, y, fma2(q.b1, xx, z1));
    z1 = fma2(-q.a2, y, fma2(q.b2, xx, z2));
    z2 = fma2(-q.a3, y, fma2(q.b3, xx, z3));
    z3 = fma2(-q.a4, y, q.b4 * xx);
    return y;
}

// Scalar variants (kernel A only).
struct Coef { float b0, b1, b2, b3, b4, a1, a2, a3, a4; };
__device__ __forceinline__ Coef load_coef(const float* __restrict__ B,
                                          const float* __restrict__ A, int c) {
    Coef q;
    q.b0 = B[c * 5 + 0]; q.b1 = B[c * 5 + 1]; q.b2 = B[c * 5 + 2];
    q.b3 = B[c * 5 + 3]; q.b4 = B[c * 5 + 4];
    q.a1 = A[c * 5 + 1]; q.a2 = A[c * 5 + 2];
    q.a3 = A[c * 5 + 3]; q.a4 = A[c * 5 + 4];
    return q;
}
__device__ __forceinline__ float iir_step(const Coef& q, float x,
                                          float& z0, float& z1, float& z2, float& z3) {
    float y = fmaf(q.b0, x, z0);
    z0 = fmaf(-q.a1, y, fmaf(q.b1, x, z1));
    z1 = fmaf(-q.a2, y, fmaf(q.b2, x, z2));
    z2 = fmaf(-q.a3, y, fmaf(q.b3, x, z3));
    z3 = fmaf(-q.a4, y, q.b4 * x);
    return y;
}

// ---------------------------------------------------------------------------
// Kernel A: per (c, b, half-chunk h) zero-state order-4 IIR over 128 samples
// -> final 4-state (forced response). LDS-staged x (proven pattern).
// zs layout: float4 at [h * NSEQ + (c*BS+b)], h in [0, NH).
// ---------------------------------------------------------------------------
__global__ __launch_bounds__(192, 4) void kA_forced_state(
        const float* __restrict__ wav, const float* __restrict__ B,
        const float* __restrict__ A, float* __restrict__ zs) {
    __shared__ float xs[HALF];
    int blk = blockIdx.x;            // b * NH + h
    int b = blk / NH;
    int h = blk - b * NH;
    const float* xg = wav + (size_t)b * TLEN + (size_t)h * HALF;
    if (threadIdx.x < HALF) xs[threadIdx.x] = xg[threadIdx.x];
    __syncthreads();
    int c = threadIdx.x;
    if (c >= NCH) return;
    Coef q = load_coef(B, A, c);
    float z0 = 0.f, z1 = 0.f, z2 = 0.f, z3 = 0.f;
    #pragma unroll 8
    for (int j = 0; j < HALF; ++j) {
        (void)iir_step(q, xs[j], z0, z1, z2, z3);
    }
    ((float4*)zs)[(size_t)h * NSEQ + (c * BS + b)] = make_float4(z0, z1, z2, z3);
}

// ---------------------------------------------------------------------------
// Kernel B: per (c,b) sequence — M^128 by repeated squaring (7 squarings),
// then scan 500 half-chunk states in place (k-major, prefetch-pipelined).
//   z_in[h] = M^HALF * z_in[h-1] + d[h-1],  z_in[0] = 0.
// ---------------------------------------------------------------------------
#define KB_PROC(d, kk)                                                         \
    {                                                                          \
        zb[(size_t)(kk) * NSEQ + id] = make_float4(s0, s1, s2, s3);            \
        float n0 = fmaf(M00, s0, fmaf(M01, s1, fmaf(M02, s2, fmaf(M03, s3, (d).x)))); \
        float n1 = fmaf(M10, s0, fmaf(M11, s1, fmaf(M12, s2, fmaf(M13, s3, (d).y)))); \
        float n2 = fmaf(M20, s0, fmaf(M21, s1, fmaf(M22, s2, fmaf(M23, s3, (d).z)))); \
        float n3 = fmaf(M30, s0, fmaf(M31, s1, fmaf(M32, s2, fmaf(M33, s3, (d).w)))); \
        s0 = n0; s1 = n1; s2 = n2; s3 = n3;                                    \
    }

__global__ __launch_bounds__(64) void kB_state_scan(
        const float* __restrict__ A, float* __restrict__ zs) {
    int id = blockIdx.x * 64 + threadIdx.x;   // c * BS + b
    if (id >= NSEQ) return;
    int c = id / BS;
    float a1 = A[c * 5 + 1], a2 = A[c * 5 + 2], a3 = A[c * 5 + 3], a4 = A[c * 5 + 4];
    float M00 = -a1, M01 = 1.f, M02 = 0.f, M03 = 0.f;
    float M10 = -a2, M11 = 0.f, M12 = 1.f, M13 = 0.f;
    float M20 = -a3, M21 = 0.f, M22 = 0.f, M23 = 1.f;
    float M30 = -a4, M31 = 0.f, M32 = 0.f, M33 = 0.f;
    for (int s = 0; s < 7; ++s) {        // M^(2^7) = M^128
        float R00 = fmaf(M00, M00, fmaf(M01, M10, fmaf(M02, M20, M03 * M30)));
        float R01 = fmaf(M00, M01, fmaf(M01, M11, fmaf(M02, M21, M03 * M31)));
        float R02 = fmaf(M00, M02, fmaf(M01, M12, fmaf(M02, M22, M03 * M32)));
        float R03 = fmaf(M00, M03, fmaf(M01, M13, fmaf(M02, M23, M03 * M33)));
        float R10 = fmaf(M10, M00, fmaf(M11, M10, fmaf(M12, M20, M13 * M30)));
        float R11 = fmaf(M10, M01, fmaf(M11, M11, fmaf(M12, M21, M13 * M31)));
        float R12 = fmaf(M10, M02, fmaf(M11, M12, fmaf(M12, M22, M13 * M32)));
        float R13 = fmaf(M10, M03, fmaf(M11, M13, fmaf(M12, M23, M13 * M33)));
        float R20 = fmaf(M20, M00, fmaf(M21, M10, fmaf(M22, M20, M23 * M30)));
        float R21 = fmaf(M20, M01, fmaf(M21, M11, fmaf(M22, M21, M23 * M31)));
        float R22 = fmaf(M20, M02, fmaf(M21, M12, fmaf(M22, M22, M23 * M32)));
        float R23 = fmaf(M20, M03, fmaf(M21, M13, fmaf(M22, M23, M23 * M33)));
        float R30 = fmaf(M30, M00, fmaf(M31, M10, fmaf(M32, M20, M33 * M30)));
        float R31 = fmaf(M30, M01, fmaf(M31, M11, fmaf(M32, M21, M33 * M31)));
        float R32 = fmaf(M30, M02, fmaf(M31, M12, fmaf(M32, M22, M33 * M32)));
        float R33 = fmaf(M30, M03, fmaf(M31, M13, fmaf(M32, M23, M33 * M33)));
        M00 = R00; M01 = R01; M02 = R02; M03 = R03;
        M10 = R10; M11 = R11; M12 = R12; M13 = R13;
        M20 = R20; M21 = R21; M22 = R22; M23 = R23;
        M30 = R30; M31 = R31; M32 = R32; M33 = R33;
    }
    float4* zb = (float4*)zs;
    float s0 = 0.f, s1 = 0.f, s2 = 0.f, s3 = 0.f;
    float4 c0 = zb[(size_t)0 * NSEQ + id];
    float4 c1 = zb[(size_t)1 * NSEQ + id];
    float4 c2 = zb[(size_t)2 * NSEQ + id];
    float4 c3 = zb[(size_t)3 * NSEQ + id];
    float4 c4 = zb[(size_t)4 * NSEQ + id];
    for (int k = 0; k < NH; k += 5) {          // 500 = 5*100
        float4 p0 = c0, p1 = c1, p2 = c2, p3 = c3, p4 = c4;
        if (k + 5 < NH) {
            p0 = zb[(size_t)(k + 5) * NSEQ + id];
            p1 = zb[(size_t)(k + 6) * NSEQ + id];
            p2 = zb[(size_t)(k + 7) * NSEQ + id];
            p3 = zb[(size_t)(k + 8) * NSEQ + id];
            p4 = zb[(size_t)(k + 9) * NSEQ + id];
        }
        KB_PROC(c0, k + 0);
        KB_PROC(c1, k + 1);
        KB_PROC(c2, k + 2);
        KB_PROC(c3, k + 3);
        KB_PROC(c4, k + 4);
        c0 = p0; c1 = p1; c2 = p2; c3 = p3; c4 = p4;
    }
}

// ---------------------------------------------------------------------------
// Kernel C (combined):
// Blocks [0, EDGE_BLOCKS): channel-128 path — one thread per (b,k), packed
//   chains {127,128}, scalar global x reads. Dispatched first (hides under
//   the main blocks).
// Blocks [EDGE_BLOCKS, +NBK): pair-channel main — one wave per (b,k); lane t
//   runs packed chains {2t, 2t+1} from the EXACT state at sample 256k-128,
//   128 full warm-up steps (beta^128 = e^-16 truncation), then 256 main
//   steps. shfl consumption is pipelined one step (ge applied with delay,
//   exact tail fixup). x staged in LDS float4, ds_read_b128 per 4 steps.
// G/y4f layout: [(b*NFRM+k)*NCH + c].
// ---------------------------------------------------------------------------

// warm step: IIR + sigmoid + beta accumulation, both chains.
#define WSTEP(xv)                                                              \
    { f2 y_ = iir2_step(q, (xv), z0, z1, z2, z3);                              \
      u = fma2(beta2, u, sig2(y_)); }

// normal main step with delayed ge consumption.
#define MSTEP(xv)                                                              \
    { f2 y_ = iir2_step(q, (xv), z0, z1, z2, z3);                              \
      u = fma2(beta2, u, sig2(y_));                                            \
      float un_ = __shfl_down(u.x, 1, 64);                                     \
      float y4o_ = fmaxf(u.y - u.x, 0.0f);                                     \
      float y4e_ = fmaxf(pend_un - pend_ub, 0.0f);                             \
      g2 = fma2(alpha2, g2, mk2(y4o_, y4e_));                                  \
      pend_un = un_; pend_ub = u.y; }

__global__ __launch_bounds__(64, 4) void kC_main(
        const float* __restrict__ wav, const float* __restrict__ B,
        const float* __restrict__ A, const float* __restrict__ zs,
        float* __restrict__ G, float* __restrict__ y4f,
        float beta, float alpha) {
    __shared__ float4 xs4[3 * HALF / 4];
    int blk = blockIdx.x;
    const f2 beta2 = mk2(beta, beta);
    const f2 alpha2 = mk2(alpha, alpha);

    if (blk < EDGE_BLOCKS) {
        // ---- edge: channel 128, one thread per (b,k), packed {127,128} ----
        int item = blk * 64 + threadIdx.x;   // b * NFRM + k
        if (item >= NBK) return;
        int b = item / NFRM;
        int k = item - b * NFRM;
        C2 q = load_coef2(B, A, 127, 128);
        f2 z0 = mk2(0.f, 0.f), z1 = z0, z2 = z0, z3 = z0, u = z0;
        const float* xg;
        if (k > 0) {
            float4 vx = ((const float4*)zs)[(size_t)(2 * k - 1) * NSEQ + (127 * BS + b)];
            float4 vy = ((const float4*)zs)[(size_t)(2 * k - 1) * NSEQ + (128 * BS + b)];
            z0 = mk2(vx.x, vy.x); z1 = mk2(vx.y, vy.y);
            z2 = mk2(vx.z, vy.z); z3 = mk2(vx.w, vy.w);
            xg = wav + (size_t)b * TLEN + ((size_t)k * LFRM - HALF);
            #pragma unroll 2
            for (int j = 0; j < HALF; ++j) {
                float x = xg[j];
                WSTEP(x);
            }
            xg += HALF;
        } else {
            xg = wav + (size_t)b * TLEN;
        }
        float g4 = 0.f, yfirst = 0.f;
        #pragma unroll 2
        for (int j = 0; j < LFRM; ++j) {
            float x = xg[j];
            f2 y_ = iir2_step(q, x, z0, z1, z2, z3);
            u = fma2(beta2, u, sig2(y_));
            float y4 = fmaxf(u.y - u.x, 0.0f);   // ch128 - ch127
            if (j == 0) yfirst = y4;
            g4 = fmaf(alpha, g4, y4);
        }
        size_t idx = (size_t)item * NCH + 128;
        G[idx] = g4;
        y4f[idx] = yfirst;
        return;
    }

    // ---- main: one wave per (b,k); lane t -> packed chains {2t, 2t+1} ----
    int mblk = blk - EDGE_BLOCKS;            // b * NFRM + k
    int b = mblk / NFRM;
    int k = mblk - b * NFRM;
    int n4 = (k > 0) ? (3 * HALF / 4) : (LFRM / 4);
    const float* xg = wav + (size_t)b * TLEN +
                      ((k > 0) ? ((size_t)k * LFRM - HALF) : (size_t)0);
    for (int i = threadIdx.x; i < n4; i += 64) xs4[i] = ((const float4*)xg)[i];
    __syncthreads();

    int t = threadIdx.x;                     // 0..63
    int cA = 2 * t, cB = 2 * t + 1;          // chains (cB <= 127)
    C2 q = load_coef2(B, A, cA, cB);         // .x = even chain, .y = odd chain
    f2 z0 = mk2(0.f, 0.f), z1 = z0, z2 = z0, z3 = z0, u = z0;
    int gbase = 0;
    if (k > 0) {
        float4 vx = ((const float4*)zs)[(size_t)(2 * k - 1) * NSEQ + (cA * BS + b)];
        float4 vy = ((const float4*)zs)[(size_t)(2 * k - 1) * NSEQ + (cB * BS + b)];
        z0 = mk2(vx.x, vy.x); z1 = mk2(vx.y, vy.y);
        z2 = mk2(vx.z, vy.z); z3 = mk2(vx.w, vy.w);
        // warm-up: 128 full steps (IIR + sigmoid + beta) from exact state
        for (int g = 0; g < HALF / 4; ++g) {
            float4 xq = xs4[g];
            WSTEP(xq.x); WSTEP(xq.y); WSTEP(xq.z); WSTEP(xq.w);
        }
        gbase = HALF / 4;
    }

    // main 256 steps; pipeline: ge consumes shfl one step late.
    f2 g2;
    float fo, fe, pend_un, pend_ub;
    {   // first group: peel j=0 and j=1
        float4 xq = xs4[gbase];
        // j = 0
        f2 y_ = iir2_step(q, xq.x, z0, z1, z2, z3);
        u = fma2(beta2, u, sig2(y_));
        float un_ = __shfl_down(u.x, 1, 64);
        float y4o_ = fmaxf(u.y - u.x, 0.0f);
        fo = y4o_;
        g2 = mk2(y4o_, 0.0f);
        pend_un = un_; pend_ub = u.y;
        // j = 1
        y_ = iir2_step(q, xq.y, z0, z1, z2, z3);
        u = fma2(beta2, u, sig2(y_));
        un_ = __shfl_down(u.x, 1, 64);
        y4o_ = fmaxf(u.y - u.x, 0.0f);
        float y4e_ = fmaxf(pend_un - pend_ub, 0.0f);
        fe = y4e_;                            // y4e at j=0
        g2 = fma2(alpha2, g2, mk2(y4o_, y4e_));
        pend_un = un_; pend_ub = u.y;
        // j = 2, 3
        MSTEP(xq.z); MSTEP(xq.w);
    }
    for (int g = gbase + 1; g < gbase + LFRM / 4; ++g) {
        float4 xq = xs4[g];
        MSTEP(xq.x); MSTEP(xq.y); MSTEP(xq.z); MSTEP(xq.w);
    }
    // tail: apply the last pending ge term (j = 255)
    float y4e_last = fmaxf(pend_un - pend_ub, 0.0f);
    float go = g2.x;
    float ge = fmaf(alpha, g2.y, y4e_last);

    size_t base = (size_t)mblk * NCH;
    G[base + cB] = go;            // channel 2t+1 (odd 1..127)
    y4f[base + cB] = fo;
    if (t < 63) {
        G[base + cB + 1] = ge;    // channel 2t+2 (even 2..126)
        y4f[base + cB + 1] = fe;
    }
}

// ---------------------------------------------------------------------------
// Kernel D: per (b,c) exclusive alpha-scan over chunks, prefetch-pipelined.
//   y5[256k] = alpha * s_in[k] + y4[256k];  s_in[k+1] = alpha^L s_in[k] + G[k].
// ---------------------------------------------------------------------------
__global__ __launch_bounds__(64) void kD_alpha_scan(
        const float* __restrict__ G, const float* __restrict__ y4f,
        float* __restrict__ out, float alpha, float alphaL) {
    int id = blockIdx.x * 64 + threadIdx.x;   // b * NCH + c
    if (id >= NSEQ) return;
    int b = id / NCH;
    int c = id - b * NCH;
    float* o = out + (size_t)id * NFRM;       // (BS, NCH, NFRM) row
    if (c == 0) {
        for (int k = 0; k < NFRM; ++k) o[k] = 0.0f;
        return;
    }
    size_t i0 = (size_t)b * NFRM * NCH + c;
    float s = 0.f;
    float cg0 = G[i0 + 0 * NCH], cy0 = y4f[i0 + 0 * NCH];
    float cg1 = G[i0 + 1 * NCH], cy1 = y4f[i0 + 1 * NCH];
    float cg2 = G[i0 + 2 * NCH], cy2 = y4f[i0 + 2 * NCH];
    float cg3 = G[i0 + 3 * NCH], cy3 = y4f[i0 + 3 * NCH];
    float cg4 = G[i0 + 4 * NCH], cy4 = y4f[i0 + 4 * NCH];
    for (int k = 0; k < NFRM; k += 5) {       // 250 = 5*50
        float pg0 = cg0, py0 = cy0, pg1 = cg1, py1 = cy1, pg2 = cg2, py2 = cy2;
        float pg3 = cg3, py3 = cy3, pg4 = cg4, py4 = cy4;
        if (k + 5 < NFRM) {
            size_t ip = i0 + (size_t)(k + 5) * NCH;
            pg0 = G[ip + 0 * NCH]; py0 = y4f[ip + 0 * NCH];
            pg1 = G[ip + 1 * NCH]; py1 = y4f[ip + 1 * NCH];
            pg2 = G[ip + 2 * NCH]; py2 = y4f[ip + 2 * NCH];
            pg3 = G[ip + 3 * NCH]; py3 = y4f[ip + 3 * NCH];
            pg4 = G[ip + 4 * NCH]; py4 = y4f[ip + 4 * NCH];
        }
        o[k + 0] = fmaf(alpha, s, cy0); s = fmaf(alphaL, s, cg0);
        o[k + 1] = fmaf(alpha, s, cy1); s = fmaf(alphaL, s, cg1);
        o[k + 2] = fmaf(alpha, s, cy2); s = fmaf(alphaL, s, cg2);
        o[k + 3] = fmaf(alpha, s, cy3); s = fmaf(alphaL, s, cg3);
        o[k + 4] = fmaf(alpha, s, cy4); s = fmaf(alphaL, s, cg4);
        cg0 = pg0; cy0 = py0; cg1 = pg1; cy1 = py1; cg2 = pg2; cy2 = py2;
        cg3 = pg3; cy3 = py3; cg4 = pg4; cy4 = py4;
    }
}

// ---------------------------------------------------------------------------
extern "C" void kernel_launch(void* const* d_in, const int* in_sizes, int n_in,
                              void* d_out, int out_size, void* d_ws, size_t ws_size,
                              hipStream_t stream) {
    const float* wav = (const float*)d_in[0];   // (BS, TLEN)
    const float* Bc  = (const float*)d_in[1];   // (NCH, 5)
    const float* Ac  = (const float*)d_in[2];   // (NCH, 5)
    float* out = (float*)d_out;                 // (BS, NCH, NFRM)

    // workspace: zs (NH*NSEQ float4 = 8.26 MB) | G (NBK*NCH) | y4f (NBK*NCH)
    float* zs  = (float*)d_ws;
    float* G   = zs + (size_t)NH * NSEQ * 4;
    float* y4f = G + (size_t)NBK * NCH;

    const float alpha  = (float)exp(-1.0 / 128.0);
    const float beta   = (float)exp(-1.0 / 8.0);
    const float alphaL = (float)exp(-256.0 / 128.0);

    kA_forced_state<<<BS * NH, 192, 0, stream>>>(wav, Bc, Ac, zs);
    kB_state_scan<<<(NSEQ + 63) / 64, 64, 0, stream>>>(Ac, zs);
    kC_main<<<EDGE_BLOCKS + NBK, 64, 0, stream>>>(wav, Bc, Ac, zs, G, y4f, beta, alpha);
    kD_alpha_scan<<<(NSEQ + 63) / 64, 64, 0, stream>>>(G, y4f, out, alpha, alphaL);
}

// Round 7
// 201.425 us; speedup vs baseline: 3.4332x; 1.0126x over previous
//
#include <hip/hip_runtime.h>
#include <math.h>

// Problem constants (from reference)
#define NCH 129
#define BS 8
#define TLEN 64000
#define HALF 128          // state granularity AND kC tile length
#define NH 500            // TLEN / HALF
#define LFRM 256          // frame stride
#define NFRM 250          // number of frames
#define NSEQ (NCH * BS)   // 1032 sequences
#define NBK (BS * NFRM)   // 2000 (b,frame) cells
#define NT (BS * NH)      // 4000 (b,tile) cells
#define EDGE_BLOCKS 63    // ceil(NT/64): channel-128 path blocks
#define KA_EDGE 63        // ceil(NT/64): kA channel-128 blocks

typedef float f2 __attribute__((ext_vector_type(2)));

__device__ __forceinline__ f2 mk2(float a, float b) { f2 r; r.x = a; r.y = b; return r; }

__device__ __forceinline__ f2 fma2(f2 a, f2 b, f2 c) {
#if __has_builtin(__builtin_elementwise_fma)
    return __builtin_elementwise_fma(a, b, c);
#else
    f2 r; r.x = fmaf(a.x, b.x, c.x); r.y = fmaf(a.y, b.y, c.y); return r;
#endif
}

__device__ __forceinline__ f2 sig2(f2 v) {
    f2 r;
    r.x = __builtin_amdgcn_rcpf(1.0f + __expf(-v.x));
    r.y = __builtin_amdgcn_rcpf(1.0f + __expf(-v.y));
    return r;
}

// Packed pair-of-chains coefficients.
struct C2 { f2 b0, b1, b2, b3, b4, a1, a2, a3, a4; };

__device__ __forceinline__ C2 load_coef2(const float* __restrict__ B,
                                         const float* __restrict__ A,
                                         int cx, int cy) {
    C2 q;
    q.b0 = mk2(B[cx * 5 + 0], B[cy * 5 + 0]);
    q.b1 = mk2(B[cx * 5 + 1], B[cy * 5 + 1]);
    q.b2 = mk2(B[cx * 5 + 2], B[cy * 5 + 2]);
    q.b3 = mk2(B[cx * 5 + 3], B[cy * 5 + 3]);
    q.b4 = mk2(B[cx * 5 + 4], B[cy * 5 + 4]);
    q.a1 = mk2(A[cx * 5 + 1], A[cy * 5 + 1]);
    q.a2 = mk2(A[cx * 5 + 2], A[cy * 5 + 2]);
    q.a3 = mk2(A[cx * 5 + 3], A[cy * 5 + 3]);
    q.a4 = mk2(A[cx * 5 + 4], A[cy * 5 + 4]);
    return q;
}

__device__ __forceinline__ f2 iir2_step(const C2& q, float x,
                                        f2& z0, f2& z1, f2& z2, f2& z3) {
    f2 xx = mk2(x, x);
    f2 y = fma2(q.b0, xx, z0);
    z0 = fma2(-q.a1, y, fma2(q.b1, xx, z1));
    z1 = fma2(-q.a2, y, fma2(q.b2, xx, z2));
    z2 = fma2(-q.a3, y, fma2(q.b3, xx, z3));
    z3 = fma2(-q.a4, y, q.b4 * xx);
    return y;
}

// Scalar variants (kernel A only).
struct Coef { float b0, b1, b2, b3, b4, a1, a2, a3, a4; };
__device__ __forceinline__ Coef load_coef(const float* __restrict__ B,
                                          const float* __restrict__ A, int c) {
    Coef q;
    q.b0 = B[c * 5 + 0]; q.b1 = B[c * 5 + 1]; q.b2 = B[c * 5 + 2];
    q.b3 = B[c * 5 + 3]; q.b4 = B[c * 5 + 4];
    q.a1 = A[c * 5 + 1]; q.a2 = A[c * 5 + 2];
    q.a3 = A[c * 5 + 3]; q.a4 = A[c * 5 + 4];
    return q;
}
__device__ __forceinline__ float iir_step(const Coef& q, float x,
                                          float& z0, float& z1, float& z2, float& z3) {
    float y = fmaf(q.b0, x, z0);
    z0 = fmaf(-q.a1, y, fmaf(q.b1, x, z1));
    z1 = fmaf(-q.a2, y, fmaf(q.b2, x, z2));
    z2 = fmaf(-q.a3, y, fmaf(q.b3, x, z3));
    z3 = fmaf(-q.a4, y, q.b4 * x);
    return y;
}

// step macros for packed chains
#define ISTEP(xv) { (void)iir2_step(q, (xv), z0, z1, z2, z3); }
#define WSTEP(xv)                                                              \
    { f2 y_ = iir2_step(q, (xv), z0, z1, z2, z3);                              \
      u = fma2(beta2, u, sig2(y_)); }
#define MSTEP(xv)                                                              \
    { f2 y_ = iir2_step(q, (xv), z0, z1, z2, z3);                              \
      u = fma2(beta2, u, sig2(y_));                                            \
      float un_ = __shfl_down(u.x, 1, 64);                                     \
      float y4o_ = fmaxf(u.y - u.x, 0.0f);                                     \
      float y4e_ = fmaxf(pend_un - pend_ub, 0.0f);                             \
      g2 = fma2(alpha2, g2, mk2(y4o_, y4e_));                                  \
      pend_un = un_; pend_ub = u.y; }

// ---------------------------------------------------------------------------
// Kernel A: forced-response state per (c, b, half-chunk h).
// Blocks [0, KA_EDGE): channel 128 — one (b,h) item per lane, scalar x reads.
// Blocks [KA_EDGE, +NT): channels 0..127 — 128 threads, LDS-staged x.
// zs layout: float4 at [h * NSEQ + (c*BS+b)]; after kB it holds the exact
// state at sample 128h.
// ---------------------------------------------------------------------------
__global__ __launch_bounds__(128, 4) void kA_forced_state(
        const float* __restrict__ wav, const float* __restrict__ B,
        const float* __restrict__ A, float* __restrict__ zs) {
    __shared__ float xs[HALF];
    int blk = blockIdx.x;
    if (blk < KA_EDGE) {
        int item = blk * 64 + threadIdx.x;   // only wave 0 does work
        if (threadIdx.x >= 64 || item >= NT) return;
        int b = item / NH;
        int h = item - b * NH;
        const float* xg = wav + (size_t)b * TLEN + (size_t)h * HALF;
        Coef q = load_coef(B, A, 128);
        float z0 = 0.f, z1 = 0.f, z2 = 0.f, z3 = 0.f;
        #pragma unroll 4
        for (int j = 0; j < HALF; ++j) {
            (void)iir_step(q, xg[j], z0, z1, z2, z3);
        }
        ((float4*)zs)[(size_t)h * NSEQ + (128 * BS + b)] = make_float4(z0, z1, z2, z3);
        return;
    }
    int mblk = blk - KA_EDGE;        // b * NH + h
    int b = mblk / NH;
    int h = mblk - b * NH;
    const float* xg = wav + (size_t)b * TLEN + (size_t)h * HALF;
    xs[threadIdx.x] = xg[threadIdx.x];
    __syncthreads();
    int c = threadIdx.x;             // 0..127
    Coef q = load_coef(B, A, c);
    float z0 = 0.f, z1 = 0.f, z2 = 0.f, z3 = 0.f;
    #pragma unroll 8
    for (int j = 0; j < HALF; ++j) {
        (void)iir_step(q, xs[j], z0, z1, z2, z3);
    }
    ((float4*)zs)[(size_t)h * NSEQ + (c * BS + b)] = make_float4(z0, z1, z2, z3);
}

// ---------------------------------------------------------------------------
// Kernel B: per (c,b) sequence — M^128 by repeated squaring, then scan 500
// half-chunk states in place (k-major, prefetch-pipelined).
// ---------------------------------------------------------------------------
#define KB_PROC(d, kk)                                                         \
    {                                                                          \
        zb[(size_t)(kk) * NSEQ + id] = make_float4(s0, s1, s2, s3);            \
        float n0 = fmaf(M00, s0, fmaf(M01, s1, fmaf(M02, s2, fmaf(M03, s3, (d).x)))); \
        float n1 = fmaf(M10, s0, fmaf(M11, s1, fmaf(M12, s2, fmaf(M13, s3, (d).y)))); \
        float n2 = fmaf(M20, s0, fmaf(M21, s1, fmaf(M22, s2, fmaf(M23, s3, (d).z)))); \
        float n3 = fmaf(M30, s0, fmaf(M31, s1, fmaf(M32, s2, fmaf(M33, s3, (d).w)))); \
        s0 = n0; s1 = n1; s2 = n2; s3 = n3;                                    \
    }

__global__ __launch_bounds__(64) void kB_state_scan(
        const float* __restrict__ A, float* __restrict__ zs) {
    int id = blockIdx.x * 64 + threadIdx.x;   // c * BS + b
    if (id >= NSEQ) return;
    int c = id / BS;
    float a1 = A[c * 5 + 1], a2 = A[c * 5 + 2], a3 = A[c * 5 + 3], a4 = A[c * 5 + 4];
    float M00 = -a1, M01 = 1.f, M02 = 0.f, M03 = 0.f;
    float M10 = -a2, M11 = 0.f, M12 = 1.f, M13 = 0.f;
    float M20 = -a3, M21 = 0.f, M22 = 0.f, M23 = 1.f;
    float M30 = -a4, M31 = 0.f, M32 = 0.f, M33 = 0.f;
    for (int s = 0; s < 7; ++s) {        // M^(2^7) = M^128
        float R00 = fmaf(M00, M00, fmaf(M01, M10, fmaf(M02, M20, M03 * M30)));
        float R01 = fmaf(M00, M01, fmaf(M01, M11, fmaf(M02, M21, M03 * M31)));
        float R02 = fmaf(M00, M02, fmaf(M01, M12, fmaf(M02, M22, M03 * M32)));
        float R03 = fmaf(M00, M03, fmaf(M01, M13, fmaf(M02, M23, M03 * M33)));
        float R10 = fmaf(M10, M00, fmaf(M11, M10, fmaf(M12, M20, M13 * M30)));
        float R11 = fmaf(M10, M01, fmaf(M11, M11, fmaf(M12, M21, M13 * M31)));
        float R12 = fmaf(M10, M02, fmaf(M11, M12, fmaf(M12, M22, M13 * M32)));
        float R13 = fmaf(M10, M03, fmaf(M11, M13, fmaf(M12, M23, M13 * M33)));
        float R20 = fmaf(M20, M00, fmaf(M21, M10, fmaf(M22, M20, M23 * M30)));
        float R21 = fmaf(M20, M01, fmaf(M21, M11, fmaf(M22, M21, M23 * M31)));
        float R22 = fmaf(M20, M02, fmaf(M21, M12, fmaf(M22, M22, M23 * M32)));
        float R23 = fmaf(M20, M03, fmaf(M21, M13, fmaf(M22, M23, M23 * M33)));
        float R30 = fmaf(M30, M00, fmaf(M31, M10, fmaf(M32, M20, M33 * M30)));
        float R31 = fmaf(M30, M01, fmaf(M31, M11, fmaf(M32, M21, M33 * M31)));
        float R32 = fmaf(M30, M02, fmaf(M31, M12, fmaf(M32, M22, M33 * M32)));
        float R33 = fmaf(M30, M03, fmaf(M31, M13, fmaf(M32, M23, M33 * M33)));
        M00 = R00; M01 = R01; M02 = R02; M03 = R03;
        M10 = R10; M11 = R11; M12 = R12; M13 = R13;
        M20 = R20; M21 = R21; M22 = R22; M23 = R23;
        M30 = R30; M31 = R31; M32 = R32; M33 = R33;
    }
    float4* zb = (float4*)zs;
    float s0 = 0.f, s1 = 0.f, s2 = 0.f, s3 = 0.f;
    float4 c0 = zb[(size_t)0 * NSEQ + id];
    float4 c1 = zb[(size_t)1 * NSEQ + id];
    float4 c2 = zb[(size_t)2 * NSEQ + id];
    float4 c3 = zb[(size_t)3 * NSEQ + id];
    float4 c4 = zb[(size_t)4 * NSEQ + id];
    for (int k = 0; k < NH; k += 5) {          // 500 = 5*100
        float4 p0 = c0, p1 = c1, p2 = c2, p3 = c3, p4 = c4;
        if (k + 5 < NH) {
            p0 = zb[(size_t)(k + 5) * NSEQ + id];
            p1 = zb[(size_t)(k + 6) * NSEQ + id];
            p2 = zb[(size_t)(k + 7) * NSEQ + id];
            p3 = zb[(size_t)(k + 8) * NSEQ + id];
            p4 = zb[(size_t)(k + 9) * NSEQ + id];
        }
        KB_PROC(c0, k + 0);
        KB_PROC(c1, k + 1);
        KB_PROC(c2, k + 2);
        KB_PROC(c3, k + 3);
        KB_PROC(c4, k + 4);
        c0 = p0; c1 = p1; c2 = p2; c3 = p3; c4 = p4;
    }
}

// ---------------------------------------------------------------------------
// Kernel C: half-frame tiles. Tile r in [0, NH) per batch covers samples
// [128r, 128r+128); frame k = r>>1, half = r&1. Warm-up over [128(r-1),128r)
// from the EXACT state zs[r-1]: first 64 steps IIR-only (beta^64 = 3.4e-4
// truncation), last 64 full. First-half tiles emit y4f + G1 (partial alpha
// sum); second-half emit G2. Frame: G = alpha^128 G1 + G2 (kD).
// Blocks [0, EDGE_BLOCKS): channel-128 path, one (b,r) item per lane.
// Blocks [EDGE_BLOCKS, +NT): pair-channel main, one wave per (b,r); lane t
// runs packed chains {2t,2t+1}; shfl consumed one step late (tail fixup).
// ---------------------------------------------------------------------------
__global__ __launch_bounds__(64, 4) void kC_main(
        const float* __restrict__ wav, const float* __restrict__ B,
        const float* __restrict__ A, const float* __restrict__ zs,
        float* __restrict__ G1, float* __restrict__ G2,
        float* __restrict__ y4f, float beta, float alpha) {
    __shared__ float4 xs4[2 * HALF / 4];
    int blk = blockIdx.x;
    const f2 beta2 = mk2(beta, beta);
    const f2 alpha2 = mk2(alpha, alpha);

    if (blk < EDGE_BLOCKS) {
        // ---- edge: channel 128, one (b,r) per lane ----
        int item = blk * 64 + threadIdx.x;
        if (item >= NT) return;
        int b = item / NH;
        int r = item - b * NH;
        int k = r >> 1, half = r & 1;
        C2 q = load_coef2(B, A, 127, 128);
        f2 z0 = mk2(0.f, 0.f), z1 = z0, z2 = z0, z3 = z0, u = z0;
        const float* xg;
        if (r > 0) {
            float4 vx = ((const float4*)zs)[(size_t)(r - 1) * NSEQ + (127 * BS + b)];
            float4 vy = ((const float4*)zs)[(size_t)(r - 1) * NSEQ + (128 * BS + b)];
            z0 = mk2(vx.x, vy.x); z1 = mk2(vx.y, vy.y);
            z2 = mk2(vx.z, vy.z); z3 = mk2(vx.w, vy.w);
            xg = wav + (size_t)b * TLEN + (size_t)(r - 1) * HALF;
            #pragma unroll 2
            for (int j = 0; j < HALF / 2; ++j) ISTEP(xg[j]);
            #pragma unroll 2
            for (int j = HALF / 2; j < HALF; ++j) WSTEP(xg[j]);
            xg += HALF;
        } else {
            xg = wav + (size_t)b * TLEN;
        }
        float g4 = 0.f, yfirst = 0.f;
        #pragma unroll 2
        for (int j = 0; j < HALF; ++j) {
            f2 y_ = iir2_step(q, xg[j], z0, z1, z2, z3);
            u = fma2(beta2, u, sig2(y_));
            float y4 = fmaxf(u.y - u.x, 0.0f);   // ch128 - ch127
            if (j == 0) yfirst = y4;
            g4 = fmaf(alpha, g4, y4);
        }
        size_t idx = ((size_t)b * NFRM + k) * NCH + 128;
        if (half == 0) { G1[idx] = g4; y4f[idx] = yfirst; }
        else           { G2[idx] = g4; }
        return;
    }

    // ---- main: one wave per (b,r); lane t -> packed chains {2t, 2t+1} ----
    int mblk = blk - EDGE_BLOCKS;            // b * NH + r
    int b = mblk / NH;
    int r = mblk - b * NH;
    int k = r >> 1, half = r & 1;
    int n4 = (r > 0) ? (2 * HALF / 4) : (HALF / 4);
    const float* xg = wav + (size_t)b * TLEN +
                      ((r > 0) ? (size_t)(r - 1) * HALF : (size_t)0);
    if (threadIdx.x < n4) xs4[threadIdx.x] = ((const float4*)xg)[threadIdx.x];
    __syncthreads();

    int t = threadIdx.x;                     // 0..63
    int cA = 2 * t, cB = 2 * t + 1;          // chains (cB <= 127)
    C2 q = load_coef2(B, A, cA, cB);
    f2 z0 = mk2(0.f, 0.f), z1 = z0, z2 = z0, z3 = z0, u = z0;
    int gbase = 0;
    if (r > 0) {
        float4 vx = ((const float4*)zs)[(size_t)(r - 1) * NSEQ + (cA * BS + b)];
        float4 vy = ((const float4*)zs)[(size_t)(r - 1) * NSEQ + (cB * BS + b)];
        z0 = mk2(vx.x, vy.x); z1 = mk2(vx.y, vy.y);
        z2 = mk2(vx.z, vy.z); z3 = mk2(vx.w, vy.w);
        for (int g = 0; g < HALF / 8; ++g) {       // 64 steps IIR-only
            float4 xq = xs4[g];
            ISTEP(xq.x); ISTEP(xq.y); ISTEP(xq.z); ISTEP(xq.w);
        }
        for (int g = HALF / 8; g < HALF / 4; ++g) { // 64 steps full warm
            float4 xq = xs4[g];
            WSTEP(xq.x); WSTEP(xq.y); WSTEP(xq.z); WSTEP(xq.w);
        }
        gbase = HALF / 4;
    }

    // main 128 steps; pipeline: ge consumes shfl one step late.
    f2 g2;
    float fo, fe, pend_un, pend_ub;
    {   // first group: peel j=0 and j=1
        float4 xq = xs4[gbase];
        // j = 0
        f2 y_ = iir2_step(q, xq.x, z0, z1, z2, z3);
        u = fma2(beta2, u, sig2(y_));
        float un_ = __shfl_down(u.x, 1, 64);
        float y4o_ = fmaxf(u.y - u.x, 0.0f);
        fo = y4o_;
        g2 = mk2(y4o_, 0.0f);
        pend_un = un_; pend_ub = u.y;
        // j = 1
        y_ = iir2_step(q, xq.y, z0, z1, z2, z3);
        u = fma2(beta2, u, sig2(y_));
        un_ = __shfl_down(u.x, 1, 64);
        y4o_ = fmaxf(u.y - u.x, 0.0f);
        float y4e_ = fmaxf(pend_un - pend_ub, 0.0f);
        fe = y4e_;                            // y4e at j=0
        g2 = fma2(alpha2, g2, mk2(y4o_, y4e_));
        pend_un = un_; pend_ub = u.y;
        // j = 2, 3
        MSTEP(xq.z); MSTEP(xq.w);
    }
    for (int g = gbase + 1; g < gbase + HALF / 4; ++g) {
        float4 xq = xs4[g];
        MSTEP(xq.x); MSTEP(xq.y); MSTEP(xq.z); MSTEP(xq.w);
    }
    // tail: apply the last pending ge term
    float y4e_last = fmaxf(pend_un - pend_ub, 0.0f);
    float go = g2.x;
    float ge = fmaf(alpha, g2.y, y4e_last);

    size_t base = ((size_t)b * NFRM + k) * NCH;
    if (half == 0) {
        G1[base + cB] = go;            // channel 2t+1 (odd 1..127)
        y4f[base + cB] = fo;
        if (t < 63) {
            G1[base + cB + 1] = ge;    // channel 2t+2 (even 2..126)
            y4f[base + cB + 1] = fe;
        }
    } else {
        G2[base + cB] = go;
        if (t < 63) G2[base + cB + 1] = ge;
    }
}

// ---------------------------------------------------------------------------
// Kernel D: per (b,c) exclusive alpha-scan over frames, prefetch-pipelined.
//   o[k] = alpha*s + y4f[k];  s' = alpha^256 s + alpha^128 G1[k] + G2[k].
// ---------------------------------------------------------------------------
__global__ __launch_bounds__(64) void kD_alpha_scan(
        const float* __restrict__ G1, const float* __restrict__ G2,
        const float* __restrict__ y4f, float* __restrict__ out,
        float alpha, float alphaL, float alphaH) {
    int id = blockIdx.x * 64 + threadIdx.x;   // b * NCH + c
    if (id >= NSEQ) return;
    int b = id / NCH;
    int c = id - b * NCH;
    float* o = out + (size_t)id * NFRM;       // (BS, NCH, NFRM) row
    if (c == 0) {
        for (int k = 0; k < NFRM; ++k) o[k] = 0.0f;
        return;
    }
    size_t i0 = (size_t)b * NFRM * NCH + c;
    float s = 0.f;
    float cg0 = fmaf(alphaH, G1[i0 + 0 * NCH], G2[i0 + 0 * NCH]), cy0 = y4f[i0 + 0 * NCH];
    float cg1 = fmaf(alphaH, G1[i0 + 1 * NCH], G2[i0 + 1 * NCH]), cy1 = y4f[i0 + 1 * NCH];
    float cg2 = fmaf(alphaH, G1[i0 + 2 * NCH], G2[i0 + 2 * NCH]), cy2 = y4f[i0 + 2 * NCH];
    float cg3 = fmaf(alphaH, G1[i0 + 3 * NCH], G2[i0 + 3 * NCH]), cy3 = y4f[i0 + 3 * NCH];
    float cg4 = fmaf(alphaH, G1[i0 + 4 * NCH], G2[i0 + 4 * NCH]), cy4 = y4f[i0 + 4 * NCH];
    for (int k = 0; k < NFRM; k += 5) {       // 250 = 5*50
        float pg0 = cg0, py0 = cy0, pg1 = cg1, py1 = cy1, pg2 = cg2, py2 = cy2;
        float pg3 = cg3, py3 = cy3, pg4 = cg4, py4 = cy4;
        if (k + 5 < NFRM) {
            size_t ip = i0 + (size_t)(k + 5) * NCH;
            pg0 = fmaf(alphaH, G1[ip + 0 * NCH], G2[ip + 0 * NCH]); py0 = y4f[ip + 0 * NCH];
            pg1 = fmaf(alphaH, G1[ip + 1 * NCH], G2[ip + 1 * NCH]); py1 = y4f[ip + 1 * NCH];
            pg2 = fmaf(alphaH, G1[ip + 2 * NCH], G2[ip + 2 * NCH]); py2 = y4f[ip + 2 * NCH];
            pg3 = fmaf(alphaH, G1[ip + 3 * NCH], G2[ip + 3 * NCH]); py3 = y4f[ip + 3 * NCH];
            pg4 = fmaf(alphaH, G1[ip + 4 * NCH], G2[ip + 4 * NCH]); py4 = y4f[ip + 4 * NCH];
        }
        o[k + 0] = fmaf(alpha, s, cy0); s = fmaf(alphaL, s, cg0);
        o[k + 1] = fmaf(alpha, s, cy1); s = fmaf(alphaL, s, cg1);
        o[k + 2] = fmaf(alpha, s, cy2); s = fmaf(alphaL, s, cg2);
        o[k + 3] = fmaf(alpha, s, cy3); s = fmaf(alphaL, s, cg3);
        o[k + 4] = fmaf(alpha, s, cy4); s = fmaf(alphaL, s, cg4);
        cg0 = pg0; cy0 = py0; cg1 = pg1; cy1 = py1; cg2 = pg2; cy2 = py2;
        cg3 = pg3; cy3 = py3; cg4 = pg4; cy4 = py4;
    }
}

// ---------------------------------------------------------------------------
extern "C" void kernel_launch(void* const* d_in, const int* in_sizes, int n_in,
                              void* d_out, int out_size, void* d_ws, size_t ws_size,
                              hipStream_t stream) {
    const float* wav = (const float*)d_in[0];   // (BS, TLEN)
    const float* Bc  = (const float*)d_in[1];   // (NCH, 5)
    const float* Ac  = (const float*)d_in[2];   // (NCH, 5)
    float* out = (float*)d_out;                 // (BS, NCH, NFRM)

    // workspace: zs (NH*NSEQ float4 = 8.26 MB) | G1 | G2 | y4f (1.03 MB each)
    float* zs  = (float*)d_ws;
    float* G1  = zs + (size_t)NH * NSEQ * 4;
    float* G2  = G1 + (size_t)NBK * NCH;
    float* y4f = G2 + (size_t)NBK * NCH;

    const float alpha  = (float)exp(-1.0 / 128.0);
    const float beta   = (float)exp(-1.0 / 8.0);
    const float alphaL = (float)exp(-256.0 / 128.0);   // alpha^256
    const float alphaH = (float)exp(-128.0 / 128.0);   // alpha^128

    kA_forced_state<<<KA_EDGE + NT, 128, 0, stream>>>(wav, Bc, Ac, zs);
    kB_state_scan<<<(NSEQ + 63) / 64, 64, 0, stream>>>(Ac, zs);
    kC_main<<<EDGE_BLOCKS + NT, 64, 0, stream>>>(wav, Bc, Ac, zs, G1, G2, y4f, beta, alpha);
    kD_alpha_scan<<<(NSEQ + 63) / 64, 64, 0, stream>>>(G1, G2, y4f, out, alpha, alphaL, alphaH);
}

// Round 8
// 152.926 us; speedup vs baseline: 4.5220x; 1.3171x over previous
//
#include <hip/hip_runtime.h>
#include <math.h>

// Problem constants (from reference)
#define NCH 129
#define BS 8
#define TLEN 64000
#define HALF 128          // state granularity AND kC tile length
#define NH 500            // TLEN / HALF
#define LFRM 256          // frame stride
#define NFRM 250          // number of frames
#define NSEQ (NCH * BS)   // 1032 sequences
#define NBK (BS * NFRM)   // 2000 (b,frame) cells
#define NT (BS * NH)      // 4000 (b,tile) cells
#define KA_EDGE 63        // ceil(NT/64): kA channel-128 blocks
#define KC_EDGE 16        // ceil(NT/256): kC channel-128 blocks
#define KC_MAIN (NT / 4)  // 1000 main blocks (4 tiles per 256-thr block)

typedef float f2 __attribute__((ext_vector_type(2)));

__device__ __forceinline__ f2 mk2(float a, float b) { f2 r; r.x = a; r.y = b; return r; }

__device__ __forceinline__ f2 fma2(f2 a, f2 b, f2 c) {
#if __has_builtin(__builtin_elementwise_fma)
    return __builtin_elementwise_fma(a, b, c);
#else
    f2 r; r.x = fmaf(a.x, b.x, c.x); r.y = fmaf(a.y, b.y, c.y); return r;
#endif
}

__device__ __forceinline__ f2 sig2(f2 v) {
    f2 r;
    r.x = __builtin_amdgcn_rcpf(1.0f + __expf(-v.x));
    r.y = __builtin_amdgcn_rcpf(1.0f + __expf(-v.y));
    return r;
}

// Packed pair-of-chains coefficients.
struct C2 { f2 b0, b1, b2, b3, b4, a1, a2, a3, a4; };

__device__ __forceinline__ C2 load_coef2(const float* __restrict__ B,
                                         const float* __restrict__ A,
                                         int cx, int cy) {
    C2 q;
    q.b0 = mk2(B[cx * 5 + 0], B[cy * 5 + 0]);
    q.b1 = mk2(B[cx * 5 + 1], B[cy * 5 + 1]);
    q.b2 = mk2(B[cx * 5 + 2], B[cy * 5 + 2]);
    q.b3 = mk2(B[cx * 5 + 3], B[cy * 5 + 3]);
    q.b4 = mk2(B[cx * 5 + 4], B[cy * 5 + 4]);
    q.a1 = mk2(A[cx * 5 + 1], A[cy * 5 + 1]);
    q.a2 = mk2(A[cx * 5 + 2], A[cy * 5 + 2]);
    q.a3 = mk2(A[cx * 5 + 3], A[cy * 5 + 3]);
    q.a4 = mk2(A[cx * 5 + 4], A[cy * 5 + 4]);
    return q;
}

__device__ __forceinline__ f2 iir2_step(const C2& q, float x,
                                        f2& z0, f2& z1, f2& z2, f2& z3) {
    f2 xx = mk2(x, x);
    f2 y = fma2(q.b0, xx, z0);
    z0 = fma2(-q.a1, y, fma2(q.b1, xx, z1));
    z1 = fma2(-q.a2, y, fma2(q.b2, xx, z2));
    z2 = fma2(-q.a3, y, fma2(q.b3, xx, z3));
    z3 = fma2(-q.a4, y, q.b4 * xx);
    return y;
}

// Scalar variants (kernel A only).
struct Coef { float b0, b1, b2, b3, b4, a1, a2, a3, a4; };
__device__ __forceinline__ Coef load_coef(const float* __restrict__ B,
                                          const float* __restrict__ A, int c) {
    Coef q;
    q.b0 = B[c * 5 + 0]; q.b1 = B[c * 5 + 1]; q.b2 = B[c * 5 + 2];
    q.b3 = B[c * 5 + 3]; q.b4 = B[c * 5 + 4];
    q.a1 = A[c * 5 + 1]; q.a2 = A[c * 5 + 2];
    q.a3 = A[c * 5 + 3]; q.a4 = A[c * 5 + 4];
    return q;
}
__device__ __forceinline__ float iir_step(const Coef& q, float x,
                                          float& z0, float& z1, float& z2, float& z3) {
    float y = fmaf(q.b0, x, z0);
    z0 = fmaf(-q.a1, y, fmaf(q.b1, x, z1));
    z1 = fmaf(-q.a2, y, fmaf(q.b2, x, z2));
    z2 = fmaf(-q.a3, y, fmaf(q.b3, x, z3));
    z3 = fmaf(-q.a4, y, q.b4 * x);
    return y;
}

// step macros for packed chains
#define ISTEP(xv) { (void)iir2_step(q, (xv), z0, z1, z2, z3); }
#define WSTEP(xv)                                                              \
    { f2 y_ = iir2_step(q, (xv), z0, z1, z2, z3);                              \
      u = fma2(beta2, u, sig2(y_)); }
#define MSTEP(xv)                                                              \
    { f2 y_ = iir2_step(q, (xv), z0, z1, z2, z3);                              \
      u = fma2(beta2, u, sig2(y_));                                            \
      float un_ = __shfl_down(u.x, 1, 64);                                     \
      float y4o_ = fmaxf(u.y - u.x, 0.0f);                                     \
      float y4e_ = fmaxf(pend_un - pend_ub, 0.0f);                             \
      g2 = fma2(alpha2, g2, mk2(y4o_, y4e_));                                  \
      pend_un = un_; pend_ub = u.y; }

// ---- 4x4 matrix helpers over 16 NAMED scalars (no arrays -> no scratch) ----
#define MDECL(X) float X##00, X##01, X##02, X##03, X##10, X##11, X##12, X##13, \
                       X##20, X##21, X##22, X##23, X##30, X##31, X##32, X##33
#define MCOPY(D, S) D##00=S##00; D##01=S##01; D##02=S##02; D##03=S##03;        \
                    D##10=S##10; D##11=S##11; D##12=S##12; D##13=S##13;        \
                    D##20=S##20; D##21=S##21; D##22=S##22; D##23=S##23;        \
                    D##30=S##30; D##31=S##31; D##32=S##32; D##33=S##33
#define MROW(R, X, Y, i)                                                       \
    R##i##0 = fmaf(X##i##0, Y##00, fmaf(X##i##1, Y##10, fmaf(X##i##2, Y##20, X##i##3 * Y##30))); \
    R##i##1 = fmaf(X##i##0, Y##01, fmaf(X##i##1, Y##11, fmaf(X##i##2, Y##21, X##i##3 * Y##31))); \
    R##i##2 = fmaf(X##i##0, Y##02, fmaf(X##i##1, Y##12, fmaf(X##i##2, Y##22, X##i##3 * Y##32))); \
    R##i##3 = fmaf(X##i##0, Y##03, fmaf(X##i##1, Y##13, fmaf(X##i##2, Y##23, X##i##3 * Y##33)))
#define MMUL(R, X, Y) MROW(R, X, Y, 0); MROW(R, X, Y, 1); MROW(R, X, Y, 2); MROW(R, X, Y, 3)
// r (float4) = X * v (float4)
#define MV(r, X, v)                                                            \
    r.x = fmaf(X##00, v.x, fmaf(X##01, v.y, fmaf(X##02, v.z, X##03 * v.w)));   \
    r.y = fmaf(X##10, v.x, fmaf(X##11, v.y, fmaf(X##12, v.z, X##13 * v.w)));   \
    r.z = fmaf(X##20, v.x, fmaf(X##21, v.y, fmaf(X##22, v.z, X##23 * v.w)));   \
    r.w = fmaf(X##30, v.x, fmaf(X##31, v.y, fmaf(X##32, v.z, X##33 * v.w)))

// ---------------------------------------------------------------------------
// Kernel A: forced-response state per (c, b, half-chunk h).
// Blocks [0, KA_EDGE): channel 128 — one (b,h) item per lane, scalar x reads.
// Blocks [KA_EDGE, +NT): channels 0..127 — 128 threads, LDS-staged x.
// zs layout: float4 at [h * NSEQ + (c*BS+b)]; after kB it holds the exact
// state at sample 128h.
// ---------------------------------------------------------------------------
__global__ __launch_bounds__(128, 4) void kA_forced_state(
        const float* __restrict__ wav, const float* __restrict__ B,
        const float* __restrict__ A, float* __restrict__ zs) {
    __shared__ float xs[HALF];
    int blk = blockIdx.x;
    if (blk < KA_EDGE) {
        int item = blk * 64 + threadIdx.x;   // only wave 0 does work
        if (threadIdx.x >= 64 || item >= NT) return;
        int b = item / NH;
        int h = item - b * NH;
        const float* xg = wav + (size_t)b * TLEN + (size_t)h * HALF;
        Coef q = load_coef(B, A, 128);
        float z0 = 0.f, z1 = 0.f, z2 = 0.f, z3 = 0.f;
        #pragma unroll 4
        for (int j = 0; j < HALF; ++j) {
            (void)iir_step(q, xg[j], z0, z1, z2, z3);
        }
        ((float4*)zs)[(size_t)h * NSEQ + (128 * BS + b)] = make_float4(z0, z1, z2, z3);
        return;
    }
    int mblk = blk - KA_EDGE;        // b * NH + h
    int b = mblk / NH;
    int h = mblk - b * NH;
    const float* xg = wav + (size_t)b * TLEN + (size_t)h * HALF;
    xs[threadIdx.x] = xg[threadIdx.x];
    __syncthreads();
    int c = threadIdx.x;             // 0..127
    Coef q = load_coef(B, A, c);
    float z0 = 0.f, z1 = 0.f, z2 = 0.f, z3 = 0.f;
    #pragma unroll 8
    for (int j = 0; j < HALF; ++j) {
        (void)iir_step(q, xs[j], z0, z1, z2, z3);
    }
    ((float4*)zs)[(size_t)h * NSEQ + (c * BS + b)] = make_float4(z0, z1, z2, z3);
}

// ---------------------------------------------------------------------------
// Kernel B: PARALLEL exclusive scan of half-chunk states. One wave per (c,b).
// Lane l owns h in [8l, 8l+8) (512 >= NH=500, padded with d=0).
//   z_in[h] = M128 * z_in[h-1] + d[h-1],  z_in[0] = 0.
// Phase 1: lane folds its 8 d's:  e = Sum_i M128^{7-i} d_i.
// Phase 2: Kogge-Stone over lanes with uniform powers A^{2^s}, A = M128^8
//          (matrix squared in place between steps).
// Phase 3: exclusive shift (shfl_up 1), lane 0 -> 0.
// Phase 4: replay 8 local steps, storing z_in[h] (guarded).
// All matrices/vectors as named scalars (no private arrays).
// ---------------------------------------------------------------------------
#define KB_LOAD(dn, i)                                                         \
    {   int hh = h0 + (i); int hcl = (hh < NH) ? hh : (NH - 1);                \
        dn = zb[(size_t)hcl * NSEQ + id];                                      \
        if (hh >= NH) dn = make_float4(0.f, 0.f, 0.f, 0.f); }
#define KB_FOLD(dn)                                                            \
    {   float4 t_; MV(t_, M1, e);                                              \
        e.x = t_.x + dn.x; e.y = t_.y + dn.y;                                  \
        e.z = t_.z + dn.z; e.w = t_.w + dn.w; }
#define KB_REPLAY(dn, i)                                                       \
    {   int hh = h0 + (i);                                                     \
        if (hh < NH) zbw[(size_t)hh * NSEQ + id] = zz;                         \
        float4 t_; MV(t_, M1, zz);                                             \
        zz.x = t_.x + dn.x; zz.y = t_.y + dn.y;                                \
        zz.z = t_.z + dn.z; zz.w = t_.w + dn.w; }

__global__ __launch_bounds__(256) void kB_scan_par(
        const float* __restrict__ A, float* __restrict__ zs) {
    int id = blockIdx.x * 4 + (threadIdx.x >> 6);   // sequence c*BS+b
    int lane = threadIdx.x & 63;
    if (id >= NSEQ) return;
    int c = id / BS;
    float a1 = A[c * 5 + 1], a2 = A[c * 5 + 2], a3 = A[c * 5 + 3], a4 = A[c * 5 + 4];
    // companion matrix M -> M1 = M^128 via 7 squarings
    MDECL(M1);
    M100 = -a1; M101 = 1.f; M102 = 0.f; M103 = 0.f;
    M110 = -a2; M111 = 0.f; M112 = 1.f; M113 = 0.f;
    M120 = -a3; M121 = 0.f; M122 = 0.f; M123 = 1.f;
    M130 = -a4; M131 = 0.f; M132 = 0.f; M133 = 0.f;
    for (int s = 0; s < 7; ++s) {
        MDECL(T); MMUL(T, M1, M1); MCOPY(M1, T);
    }
    // P = M128^8 (segment transform) via 3 squarings
    MDECL(P);
    MCOPY(P, M1);
    for (int s = 0; s < 3; ++s) {
        MDECL(T); MMUL(T, P, P); MCOPY(P, T);
    }

    const float4* zb = (const float4*)zs;
    float4* zbw = (float4*)zs;
    int h0 = lane * 8;
    float4 d0, d1, d2, d3, d4, d5, d6, d7;
    KB_LOAD(d0, 0); KB_LOAD(d1, 1); KB_LOAD(d2, 2); KB_LOAD(d3, 3);
    KB_LOAD(d4, 4); KB_LOAD(d5, 5); KB_LOAD(d6, 6); KB_LOAD(d7, 7);

    // Phase 1: fold
    float4 e = d0;
    KB_FOLD(d1); KB_FOLD(d2); KB_FOLD(d3); KB_FOLD(d4);
    KB_FOLD(d5); KB_FOLD(d6); KB_FOLD(d7);

    // Phase 2: Kogge-Stone, uniform matrix power P = A^{2^s}
    for (int s = 0; s < 6; ++s) {
        int off = 1 << s;
        float4 src;
        src.x = __shfl_up(e.x, off, 64);
        src.y = __shfl_up(e.y, off, 64);
        src.z = __shfl_up(e.z, off, 64);
        src.w = __shfl_up(e.w, off, 64);
        if (lane < off) { src.x = 0.f; src.y = 0.f; src.z = 0.f; src.w = 0.f; }
        float4 t_; MV(t_, P, src);
        e.x += t_.x; e.y += t_.y; e.z += t_.z; e.w += t_.w;
        if (s < 5) { MDECL(T); MMUL(T, P, P); MCOPY(P, T); }
    }

    // Phase 3: exclusive shift
    float4 zz;
    zz.x = __shfl_up(e.x, 1, 64);
    zz.y = __shfl_up(e.y, 1, 64);
    zz.z = __shfl_up(e.z, 1, 64);
    zz.w = __shfl_up(e.w, 1, 64);
    if (lane == 0) { zz.x = 0.f; zz.y = 0.f; zz.z = 0.f; zz.w = 0.f; }

    // Phase 4: replay + store
    KB_REPLAY(d0, 0); KB_REPLAY(d1, 1); KB_REPLAY(d2, 2); KB_REPLAY(d3, 3);
    KB_REPLAY(d4, 4); KB_REPLAY(d5, 5); KB_REPLAY(d6, 6); KB_REPLAY(d7, 7);
}

// ---------------------------------------------------------------------------
// Kernel C: half-frame tiles, 256-thr blocks (4 tiles/block, per-wave LDS).
// Tile r in [0, NH) covers samples [128r, 128r+128); frame k = r>>1,
// half = r&1. Warm-up over [128(r-1), 128r) from the EXACT state zs[r-1]:
// 64 IIR-only steps (beta^64 = 3.4e-4 truncation) + 64 full. First-half
// tiles emit y4f + G1; second-half emit G2 (kD combines).
// Blocks [0, KC_EDGE): channel-128 path, one (b,r) item per thread.
// Blocks [KC_EDGE, +KC_MAIN): pair-channel main, wave w -> tile blk*4+w;
// lane t runs packed chains {2t,2t+1}; shfl consumed one step late.
// ---------------------------------------------------------------------------
__global__ __launch_bounds__(256, 8) void kC_main(
        const float* __restrict__ wav, const float* __restrict__ B,
        const float* __restrict__ A, const float* __restrict__ zs,
        float* __restrict__ G1, float* __restrict__ G2,
        float* __restrict__ y4f, float beta, float alpha) {
    __shared__ float4 xs4[4 * 64];   // per-wave 64-float4 segments
    int blk = blockIdx.x;
    const f2 beta2 = mk2(beta, beta);
    const f2 alpha2 = mk2(alpha, alpha);

    if (blk < KC_EDGE) {
        // ---- edge: channel 128, one (b,r) per thread ----
        int item = blk * 256 + threadIdx.x;
        if (item >= NT) return;
        int b = item / NH;
        int r = item - b * NH;
        int k = r >> 1, half = r & 1;
        C2 q = load_coef2(B, A, 127, 128);
        f2 z0 = mk2(0.f, 0.f), z1 = z0, z2 = z0, z3 = z0, u = z0;
        const float* xg;
        if (r > 0) {
            float4 vx = ((const float4*)zs)[(size_t)(r - 1) * NSEQ + (127 * BS + b)];
            float4 vy = ((const float4*)zs)[(size_t)(r - 1) * NSEQ + (128 * BS + b)];
            z0 = mk2(vx.x, vy.x); z1 = mk2(vx.y, vy.y);
            z2 = mk2(vx.z, vy.z); z3 = mk2(vx.w, vy.w);
            xg = wav + (size_t)b * TLEN + (size_t)(r - 1) * HALF;
            #pragma unroll 2
            for (int j = 0; j < HALF / 2; ++j) ISTEP(xg[j]);
            #pragma unroll 2
            for (int j = HALF / 2; j < HALF; ++j) WSTEP(xg[j]);
            xg += HALF;
        } else {
            xg = wav + (size_t)b * TLEN;
        }
        float g4 = 0.f, yfirst = 0.f;
        #pragma unroll 2
        for (int j = 0; j < HALF; ++j) {
            f2 y_ = iir2_step(q, xg[j], z0, z1, z2, z3);
            u = fma2(beta2, u, sig2(y_));
            float y4 = fmaxf(u.y - u.x, 0.0f);   // ch128 - ch127
            if (j == 0) yfirst = y4;
            g4 = fmaf(alpha, g4, y4);
        }
        size_t idx = ((size_t)b * NFRM + k) * NCH + 128;
        if (half == 0) { G1[idx] = g4; y4f[idx] = yfirst; }
        else           { G2[idx] = g4; }
        return;
    }

    // ---- main: wave w handles tile (blk-KC_EDGE)*4 + w ----
    int wave = threadIdx.x >> 6;
    int t = threadIdx.x & 63;                // lane 0..63
    int tile = (blk - KC_EDGE) * 4 + wave;   // b * NH + r, < NT
    int b = tile / NH;
    int r = tile - b * NH;
    int k = r >> 1, half = r & 1;
    int n4 = (r > 0) ? 64 : 32;
    const float* xg = wav + (size_t)b * TLEN +
                      ((r > 0) ? (size_t)(r - 1) * HALF : (size_t)0);
    float4* seg = xs4 + wave * 64;
    if (t < n4) seg[t] = ((const float4*)xg)[t];
    __syncthreads();

    int cA = 2 * t, cB = 2 * t + 1;          // chains (cB <= 127)
    C2 q = load_coef2(B, A, cA, cB);
    f2 z0 = mk2(0.f, 0.f), z1 = z0, z2 = z0, z3 = z0, u = z0;
    int gbase = 0;
    if (r > 0) {
        float4 vx = ((const float4*)zs)[(size_t)(r - 1) * NSEQ + (cA * BS + b)];
        float4 vy = ((const float4*)zs)[(size_t)(r - 1) * NSEQ + (cB * BS + b)];
        z0 = mk2(vx.x, vy.x); z1 = mk2(vx.y, vy.y);
        z2 = mk2(vx.z, vy.z); z3 = mk2(vx.w, vy.w);
        for (int g = 0; g < HALF / 8; ++g) {       // 64 steps IIR-only
            float4 xq = seg[g];
            ISTEP(xq.x); ISTEP(xq.y); ISTEP(xq.z); ISTEP(xq.w);
        }
        for (int g = HALF / 8; g < HALF / 4; ++g) { // 64 steps full warm
            float4 xq = seg[g];
            WSTEP(xq.x); WSTEP(xq.y); WSTEP(xq.z); WSTEP(xq.w);
        }
        gbase = HALF / 4;
    }

    // main 128 steps; pipeline: ge consumes shfl one step late.
    f2 g2;
    float fo, fe, pend_un, pend_ub;
    {   // first group: peel j=0 and j=1
        float4 xq = seg[gbase];
        // j = 0
        f2 y_ = iir2_step(q, xq.x, z0, z1, z2, z3);
        u = fma2(beta2, u, sig2(y_));
        float un_ = __shfl_down(u.x, 1, 64);
        float y4o_ = fmaxf(u.y - u.x, 0.0f);
        fo = y4o_;
        g2 = mk2(y4o_, 0.0f);
        pend_un = un_; pend_ub = u.y;
        // j = 1
        y_ = iir2_step(q, xq.y, z0, z1, z2, z3);
        u = fma2(beta2, u, sig2(y_));
        un_ = __shfl_down(u.x, 1, 64);
        y4o_ = fmaxf(u.y - u.x, 0.0f);
        float y4e_ = fmaxf(pend_un - pend_ub, 0.0f);
        fe = y4e_;                            // y4e at j=0
        g2 = fma2(alpha2, g2, mk2(y4o_, y4e_));
        pend_un = un_; pend_ub = u.y;
        // j = 2, 3
        MSTEP(xq.z); MSTEP(xq.w);
    }
    for (int g = gbase + 1; g < gbase + HALF / 4; ++g) {
        float4 xq = seg[g];
        MSTEP(xq.x); MSTEP(xq.y); MSTEP(xq.z); MSTEP(xq.w);
    }
    // tail: apply the last pending ge term
    float y4e_last = fmaxf(pend_un - pend_ub, 0.0f);
    float go = g2.x;
    float ge = fmaf(alpha, g2.y, y4e_last);

    size_t base = ((size_t)b * NFRM + k) * NCH;
    if (half == 0) {
        G1[base + cB] = go;            // channel 2t+1 (odd 1..127)
        y4f[base + cB] = fo;
        if (t < 63) {
            G1[base + cB + 1] = ge;    // channel 2t+2 (even 2..126)
            y4f[base + cB + 1] = fe;
        }
    } else {
        G2[base + cB] = go;
        if (t < 63) G2[base + cB + 1] = ge;
    }
}

// ---------------------------------------------------------------------------
// Kernel D: PARALLEL alpha-scan per (b,c) — one wave per sequence.
// Lane l owns frames [4l, 4l+4) (256 >= NFRM=250, padded g=0).
//   o[k] = alpha * s_in[k] + y4f[k];  s' = aL*s + g,  g = aH*G1 + G2.
// Kogge-Stone over lanes with scalar factor (aL^4)^{2^s}.
// ---------------------------------------------------------------------------
#define KD_LOAD(gn, yn, i)                                                     \
    {   int kk = k0 + (i); int kcl = (kk < NFRM) ? kk : (NFRM - 1);            \
        size_t ix = ((size_t)b * NFRM + kcl) * NCH + c;                        \
        gn = fmaf(aH, G1[ix], G2[ix]); yn = y4f[ix];                           \
        if (kk >= NFRM) { gn = 0.f; yn = 0.f; } }
#define KD_REPLAY(gn, yn, i)                                                   \
    {   int kk = k0 + (i);                                                     \
        if (kk < NFRM) o[kk] = fmaf(alpha, sv, yn);                            \
        sv = fmaf(aL, sv, gn); }

__global__ __launch_bounds__(256) void kD_scan_par(
        const float* __restrict__ G1, const float* __restrict__ G2,
        const float* __restrict__ y4f, float* __restrict__ out,
        float alpha, float aL, float aH) {
    int id = blockIdx.x * 4 + (threadIdx.x >> 6);   // b * NCH + c
    int lane = threadIdx.x & 63;
    if (id >= NSEQ) return;
    int b = id / NCH;
    int c = id - b * NCH;
    float* o = out + (size_t)id * NFRM;
    int k0 = lane * 4;
    if (c == 0) {
        #pragma unroll
        for (int i = 0; i < 4; ++i) {
            int kk = k0 + i;
            if (kk < NFRM) o[kk] = 0.0f;
        }
        return;
    }
    float g0, g1, g2v, g3, y0, y1, y2v, y3;
    KD_LOAD(g0, y0, 0); KD_LOAD(g1, y1, 1); KD_LOAD(g2v, y2v, 2); KD_LOAD(g3, y3, 3);
    // local inclusive carry
    float e = g0;
    e = fmaf(aL, e, g1);
    e = fmaf(aL, e, g2v);
    e = fmaf(aL, e, g3);
    // Kogge-Stone with factor f = (aL^4)^{2^s}
    float aL2 = aL * aL;
    float f = aL2 * aL2;                     // aL^4
    for (int s = 0; s < 6; ++s) {
        int off = 1 << s;
        float src = __shfl_up(e, off, 64);
        if (lane < off) src = 0.f;
        e = fmaf(f, src, e);
        f = f * f;
    }
    // exclusive shift
    float sv = __shfl_up(e, 1, 64);
    if (lane == 0) sv = 0.f;
    // replay + store
    KD_REPLAY(g0, y0, 0); KD_REPLAY(g1, y1, 1);
    KD_REPLAY(g2v, y2v, 2); KD_REPLAY(g3, y3, 3);
}

// ---------------------------------------------------------------------------
extern "C" void kernel_launch(void* const* d_in, const int* in_sizes, int n_in,
                              void* d_out, int out_size, void* d_ws, size_t ws_size,
                              hipStream_t stream) {
    const float* wav = (const float*)d_in[0];   // (BS, TLEN)
    const float* Bc  = (const float*)d_in[1];   // (NCH, 5)
    const float* Ac  = (const float*)d_in[2];   // (NCH, 5)
    float* out = (float*)d_out;                 // (BS, NCH, NFRM)

    // workspace: zs (NH*NSEQ float4 = 8.26 MB) | G1 | G2 | y4f (1.03 MB each)
    float* zs  = (float*)d_ws;
    float* G1  = zs + (size_t)NH * NSEQ * 4;
    float* G2  = G1 + (size_t)NBK * NCH;
    float* y4f = G2 + (size_t)NBK * NCH;

    const float alpha  = (float)exp(-1.0 / 128.0);
    const float beta   = (float)exp(-1.0 / 8.0);
    const float alphaL = (float)exp(-256.0 / 128.0);   // alpha^256 (frame step)
    const float alphaH = (float)exp(-128.0 / 128.0);   // alpha^128

    kA_forced_state<<<KA_EDGE + NT, 128, 0, stream>>>(wav, Bc, Ac, zs);
    kB_scan_par<<<NSEQ / 4, 256, 0, stream>>>(Ac, zs);
    kC_main<<<KC_EDGE + KC_MAIN, 256, 0, stream>>>(wav, Bc, Ac, zs, G1, G2, y4f, beta, alpha);
    kD_scan_par<<<NSEQ / 4, 256, 0, stream>>>(G1, G2, y4f, out, alpha, alphaL, alphaH);
}